// Round 4
// baseline (406.314 us; speedup 1.0000x reference)
//
#include <hip/hip_runtime.h>

typedef unsigned short ushort_t;
typedef __attribute__((ext_vector_type(8))) short short8;
typedef __attribute__((ext_vector_type(4))) float float4v;
typedef __attribute__((ext_vector_type(4))) ushort_t ushort4v;

#define B_ROWS 8192
#define HDIM   1024
#define GLD    5120   // G cols: [hat(c) | hat_raw | r | z | xh]

__device__ __forceinline__ float bf2f(ushort_t u) {
    return __uint_as_float(((unsigned)u) << 16);
}
__device__ __forceinline__ ushort_t f2bf(float f) {
    unsigned u = __float_as_uint(f);
    u += 0x7FFFu + ((u >> 16) & 1u);   // round-to-nearest-even
    return (ushort_t)(u >> 16);
}

// ---- one pack kernel for A, W, Whh ----------------------------------------
__global__ __launch_bounds__(256) void pack_all(
    const float* __restrict__ x, const float* __restrict__ h,
    const float* __restrict__ wc, const float* __restrict__ what,
    const float* __restrict__ wxr, const float* __restrict__ whr,
    const float* __restrict__ wxz, const float* __restrict__ whz,
    const float* __restrict__ wxh, const float* __restrict__ whh,
    ushort_t* __restrict__ A, ushort_t* __restrict__ W,
    ushort_t* __restrict__ Whh)
{
    const int bid = blockIdx.x;
    float4v v;
    ushort_t* dst;
    size_t i4;
    if (bid < 16384) {                       // ---- A = [x | hidden]
        i4 = ((size_t)bid * 256 + threadIdx.x) * 4;
        int c = (int)(i4 & 2047);
        size_t b = i4 >> 11;
        const float* src = (c < 1024) ? (x + b * 1024 + c)
                                      : (h + b * 1024 + (c - 1024));
        v = *(const float4v*)src;
        dst = A + i4;
    } else if (bid < 26624) {                // ---- W rows: wc|what|[xr|hr]|[xz|hz]|[xh|junk]
        i4 = ((size_t)(bid - 16384) * 256 + threadIdx.x) * 4;
        int j = (int)(i4 >> 11);
        int k = (int)(i4 & 2047);
        int r = j >> 10, jr = j & 1023;
        if (r == 0) {
            v = *(const float4v*)(wc + (size_t)j * 2048 + k);
        } else if (r == 1) {
            v = *(const float4v*)(what + (size_t)jr * 2048 + k);
        } else if (r == 4) {
            v = (k < 1024) ? *(const float4v*)(wxh + (size_t)jr * 1024 + k)
                           : (float4v){0.f, 0.f, 0.f, 0.f};
        } else {
            const float* p0 = (r == 2) ? wxr : wxz;
            const float* p1 = (r == 2) ? whr : whz;
            const float* p = (k < 1024) ? (p0 + (size_t)jr * 1024 + k)
                                        : (p1 + (size_t)jr * 1024 + (k - 1024));
            v = *(const float4v*)p;
        }
        dst = W + i4;
    } else {                                 // ---- Whh
        i4 = ((size_t)(bid - 26624) * 256 + threadIdx.x) * 4;
        v = *(const float4v*)(whh + i4);
        dst = Whh + i4;
    }
    ushort4v o;
#pragma unroll
    for (int t = 0; t < 4; ++t) o[t] = f2bf(v[t]);
    *(ushort4v*)dst = o;
}

// ---- GEMM1: G = A @ W^T -----------------------------------------------------
// Same schedule as R3 (verified ring/waits), register-trimmed:
// 256x256 tile, BK=64, 8 waves, quadrant 8-phase, ONE barrier per phase,
// DS/MFMA in the same barrier interval (cross-wave pipe overlap):
//   phase = {vmcnt(N); lgkmcnt(0); barrier; stage; ds_reads(P+1 frags); MFMA(P)}
// lgkm(0) BEFORE barrier => all waves' reads sampled LDS (WAR-safe stages);
// vmcnt(N) BEFORE barrier => all due stages landed (RAW-safe reads).
// Frag banks: A0->fX, A1->fY; B bank = half XOR tileparity. 96 frag VGPRs.
// ds_read addressing: 4 live VGPRs (Ard0/Ard1/Brd0/Brd1); S/H/mi fold into
// the 16-bit ds offset immediate. Zero-conflict pattern (R2-verified):
// LDS chunk c of row r holds global chunk c^(r&7); per-16-lane group each
// bank-group is hit exactly 2x (free).
// Waits: P2:vm6 P3:vm6 P4:vm4 P6:vm6 P7:vm6 P8:vm4; P1,P5 none.

#define GLOAD(gp, lp) __builtin_amdgcn_global_load_lds( \
    (const __attribute__((address_space(1))) void*)(gp), \
    (__attribute__((address_space(3))) void*)(lp), 16, 0, 0)

#define BARRIER do { __builtin_amdgcn_s_barrier(); \
    __builtin_amdgcn_sched_barrier(0); } while (0)
#define WLG do { \
    asm volatile("s_waitcnt lgkmcnt(0)" ::: "memory"); \
    __builtin_amdgcn_sched_barrier(0); } while (0)
#define WVM6 do { \
    asm volatile("s_waitcnt vmcnt(6)" ::: "memory"); \
    __builtin_amdgcn_sched_barrier(0); } while (0)
#define WVM4 do { \
    asm volatile("s_waitcnt vmcnt(4)" ::: "memory"); \
    __builtin_amdgcn_sched_barrier(0); } while (0)
#define WVM2 do { \
    asm volatile("s_waitcnt vmcnt(2)" ::: "memory"); \
    __builtin_amdgcn_sched_barrier(0); } while (0)
#define WVM0 do { \
    asm volatile("s_waitcnt vmcnt(0)" ::: "memory"); \
    __builtin_amdgcn_sched_barrier(0); } while (0)

// stage one 128x64 half-tile: 8 waves x 2 GLOADs x 1KB = 16KB
#define STAGE_A(S, H, KT) do { \
    GLOAD(A + (aO0 + (H) * 262144u + (unsigned)(KT) * 64u), dstA + (S) * 32768 + (H) * 8192); \
    GLOAD(A + (aO1 + (H) * 262144u + (unsigned)(KT) * 64u), dstA + (S) * 32768 + (H) * 8192 + 512); } while (0)
#define STAGE_B(S, H, KT) do { \
    GLOAD(B + (bO0 + (H) * 262144u + (unsigned)(KT) * 64u), dstB + (S) * 32768 + (H) * 8192); \
    GLOAD(B + (bO1 + (H) * 262144u + (unsigned)(KT) * 64u), dstB + (S) * 32768 + (H) * 8192 + 512); } while (0)

// 8 ds_read_b128: A-fragments (both kh) of one A-half into bank BK
#define RD_A(BK, S, H) do { \
    _Pragma("unroll") \
    for (int mi = 0; mi < 4; ++mi) { \
        BK[mi]     = *(const short8*)(lds + (S) * 32768 + (H) * 8192 + mi * 1024 + Ard0); \
        BK[4 + mi] = *(const short8*)(lds + (S) * 32768 + (H) * 8192 + mi * 1024 + Ard1); } } while (0)

// 4 ds_read_b128: A-fragments of one kh only
#define RD_A_KH(BK, S, H, KH) do { \
    _Pragma("unroll") \
    for (int mi = 0; mi < 4; ++mi) \
        BK[(KH) * 4 + mi] = *(const short8*)(lds + (S) * 32768 + (H) * 8192 + mi * 1024 + ((KH) ? Ard1 : Ard0)); } while (0)

// 4 ds_read_b128: B-fragments (both kh) of one B-half into bank BK
#define RD_B(BK, S, H) do { \
    _Pragma("unroll") \
    for (int ni = 0; ni < 2; ++ni) { \
        BK[ni]     = *(const short8*)(lds + (S) * 32768 + 16384 + (H) * 8192 + ni * 1024 + Brd0); \
        BK[2 + ni] = *(const short8*)(lds + (S) * 32768 + 16384 + (H) * 8192 + ni * 1024 + Brd1); } } while (0)

// 16 MFMA: one quadrant (HA,HB), both kh, from banks AB/BB
#define MM(HA, HB, AB, BB) do { \
    __builtin_amdgcn_s_setprio(1); \
    _Pragma("unroll") \
    for (int mi = 0; mi < 4; ++mi) { \
        _Pragma("unroll") \
        for (int ni = 0; ni < 2; ++ni) { \
            acc[HA][HB][mi][ni] = __builtin_amdgcn_mfma_f32_16x16x32_bf16( \
                AB[mi], BB[ni], acc[HA][HB][mi][ni], 0, 0, 0); \
            acc[HA][HB][mi][ni] = __builtin_amdgcn_mfma_f32_16x16x32_bf16( \
                AB[4 + mi], BB[2 + ni], acc[HA][HB][mi][ni], 0, 0, 0); } } \
    __builtin_amdgcn_s_setprio(0); } while (0)

__global__ __launch_bounds__(512, 2) void gemm1(
    const ushort_t* __restrict__ A, const ushort_t* __restrict__ B,
    ushort_t* __restrict__ C)
{
    // heavy blocks (K=2048) first, light (K=1024) last; XCD-striped within each
    const int bid = blockIdx.x;
    int bx, by;
    if (bid < 512) { int hI = (bid & 7) * 64 + (bid >> 3); by = hI >> 4; bx = hI & 15; }
    else           { int b = bid - 512; int lI = (b & 7) * 16 + (b >> 3); by = lI >> 2; bx = 16 + (lI & 3); }
    const int bn0 = bx * 256;
    const int bm0 = by * 256;
    const int K = (bx >= 16) ? 1024 : 2048;
    const int NIT = K >> 7;                      // 2 K-tiles (128 k) per iter

    __shared__ ushort_t lds[65536];              // 128 KiB
    // element offsets: A(s,h) = s*32768 + h*8192 ; B(s,h) = s*32768 + 16384 + h*8192

    const int t = threadIdx.x;
    const int w = t >> 6, lane = t & 63;
    const int q = lane >> 4, r16 = lane & 15;

    // ---- ds_read bases (4 live VGPRs; everything else folds into imm) ----
    const int c0 = ((q ^ (r16 & 7)) << 3);           // kh0 chunk
    const int c1 = (((4 + q) ^ (r16 & 7)) << 3);     // kh1 chunk
    const int Ard0 = ((w >> 2) * 64 + r16) * 64 + c0;
    const int Ard1 = ((w >> 2) * 64 + r16) * 64 + c1;
    const int Brd0 = ((w & 3) * 32 + r16) * 64 + c0;
    const int Brd1 = ((w & 3) * 32 + r16) * 64 + c1;

    // ---- staging: lane l of wave w writes row w*16+(l>>3), chunk (l&7)^(l>>3)
    const unsigned srow0 = (unsigned)(w * 16 + ((lane >> 3) & 7));
    const unsigned kcO = (unsigned)(((lane & 7) ^ (lane >> 3)) << 3);
    const unsigned aO0 = ((unsigned)bm0 + srow0) * 2048u + kcO;
    const unsigned aO1 = aO0 + 8u * 2048u;
    const unsigned bO0 = ((unsigned)bn0 + srow0) * 2048u + kcO;
    const unsigned bO1 = bO0 + 8u * 2048u;
    ushort_t* dstA = lds + w * 1024;
    ushort_t* dstB = lds + 16384 + w * 1024;

    float4v acc[2][2][4][2];
#pragma unroll
    for (int i = 0; i < 2; ++i)
#pragma unroll
        for (int j = 0; j < 2; ++j)
#pragma unroll
            for (int m = 0; m < 4; ++m)
#pragma unroll
                for (int n = 0; n < 2; ++n)
                    acc[i][j][m][n] = {0.f, 0.f, 0.f, 0.f};

    short8 fX[8], fY[8];         // A banks: X = A-half0, Y = A-half1
    short8 gA[4], gB[4];         // B banks: E: B0->gA,B1->gB ; O: B0->gB,B1->gA

    // ---- prologue: stage E0 fully + A(s1,0)@O0 + B(s1,1)@O0, then pre-read
    STAGE_A(0, 0, 0);
    STAGE_B(0, 1, 0);
    STAGE_B(0, 0, 0);
    STAGE_A(0, 1, 0);
    STAGE_A(1, 0, 1);
    STAGE_B(1, 1, 1);
    WVM4;               // E0's 4 halves landed (last 2 stages stay in flight)
    BARRIER;
    RD_A(fX, 0, 0);     // A0@E0 -> X
    RD_B(gA, 0, 0);     // B0@E0 -> alpha

    // ---- main loop: iterations 0..NIT-2, last peeled ----
#pragma unroll 1
    for (int it = 0; it < NIT - 1; ++it) {
        const int kO  = 2 * it + 1;
        const int kE2 = 2 * it + 2;
        const int kO2 = 2 * it + 3;
        // P1: MFMA E(A0,B0)=X*gA | stage B(s1,0)@O | read gB=B(s0,1)
        WLG; BARRIER;
        STAGE_B(1, 0, kO);
        RD_B(gB, 0, 1);
        MM(0, 0, fX, gA);
        // P2: MFMA E(A0,B1)=X*gB | stage A(s1,1)@O | read fY=A(s0,1)
        WVM6; WLG; BARRIER;
        STAGE_A(1, 1, kO);
        RD_A(fY, 0, 1);
        MM(0, 1, fX, gB);
        // P3: MFMA E(A1,B1)=Y*gB | stage A(s0,0)@E' | read fX kh0 = A(s1,0)
        WVM6; WLG; BARRIER;
        STAGE_A(0, 0, kE2);
        RD_A_KH(fX, 1, 0, 0);
        MM(1, 1, fY, gB);
        // P4: MFMA E(A1,B0)=Y*gA | stage B(s0,1)@E' | read fX kh1, gB=B(s1,0)
        WVM4; WLG; BARRIER;
        STAGE_B(0, 1, kE2);
        RD_A_KH(fX, 1, 0, 1);
        RD_B(gB, 1, 0);
        MM(1, 0, fY, gA);
        // P5: MFMA O(A0,B0)=X*gB | stage B(s0,0)@E' | read gA=B(s1,1)
        WLG; BARRIER;
        STAGE_B(0, 0, kE2);
        RD_B(gA, 1, 1);
        MM(0, 0, fX, gB);
        // P6: MFMA O(A0,B1)=X*gA | stage A(s0,1)@E' | read fY=A(s1,1)
        WVM6; WLG; BARRIER;
        STAGE_A(0, 1, kE2);
        RD_A(fY, 1, 1);
        MM(0, 1, fX, gA);
        // P7: MFMA O(A1,B1)=Y*gA | stage A(s1,0)@O' | read fX' kh0 = A(s0,0)@E'
        WVM6; WLG; BARRIER;
        STAGE_A(1, 0, kO2);
        RD_A_KH(fX, 0, 0, 0);
        MM(1, 1, fY, gA);
        // P8: MFMA O(A1,B0)=Y*gB | stage B(s1,1)@O' | read fX' kh1, gA'=B(s0,0)@E'
        WVM4; WLG; BARRIER;
        STAGE_B(1, 1, kO2);
        RD_A_KH(fX, 0, 0, 1);
        RD_B(gA, 0, 0);
        MM(1, 0, fY, gB);
    }

    // ---- peeled last iteration (E fully staged; O needs B(s1,0), A(s1,1)) ----
    {
        const int kO = 2 * (NIT - 1) + 1;
        // pP1
        WLG; BARRIER;
        STAGE_B(1, 0, kO);
        RD_B(gB, 0, 1);
        MM(0, 0, fX, gA);
        // pP2
        WVM6; WLG; BARRIER;
        STAGE_A(1, 1, kO);
        RD_A(fY, 0, 1);
        MM(0, 1, fX, gB);
        // pP3
        WVM6; WLG; BARRIER;
        RD_A_KH(fX, 1, 0, 0);
        MM(1, 1, fY, gB);
        // pP4
        WVM2; WLG; BARRIER;
        RD_A_KH(fX, 1, 0, 1);
        RD_B(gB, 1, 0);
        MM(1, 0, fY, gA);
        // pP5
        WLG; BARRIER;
        RD_B(gA, 1, 1);
        MM(0, 0, fX, gB);
        // pP6
        WVM0; WLG; BARRIER;
        RD_A(fY, 1, 1);
        MM(0, 1, fX, gA);
        // pP7
        WLG; BARRIER;
        MM(1, 1, fY, gA);
        // pP8
        WLG; BARRIER;
        MM(1, 0, fY, gB);
    }

    // C/D layout: col = lane&15, row = (lane>>4)*4 + reg  [m89/m91]
    {
        const int wm2 = w >> 2, wn2 = w & 3;
#pragma unroll
        for (int ha = 0; ha < 2; ++ha)
#pragma unroll
            for (int hb = 0; hb < 2; ++hb)
#pragma unroll
                for (int mi = 0; mi < 4; ++mi)
#pragma unroll
                    for (int ni = 0; ni < 2; ++ni)
#pragma unroll
                        for (int reg = 0; reg < 4; ++reg) {
                            int row = bm0 + ha * 128 + wm2 * 64 + mi * 16 + q * 4 + reg;
                            int col = bn0 + hb * 128 + wn2 * 32 + ni * 16 + r16;
                            C[(size_t)row * GLD + col] = f2bf(acc[ha][hb][mi][ni][reg]);
                        }
    }
}

// ---- fused row pass: softmax*relu (hat) + rh, wave-per-row, no syncs -------
__global__ __launch_bounds__(256) void row_pass(
    ushort_t* __restrict__ G, const float* __restrict__ bias_c,
    const float* __restrict__ bias_hat, const float* __restrict__ bias_r,
    const float* __restrict__ hidden, ushort_t* __restrict__ rh)
{
    const int wave = threadIdx.x >> 6, lane = threadIdx.x & 63;
    const size_t row = (size_t)blockIdx.x * 4 + wave;
    ushort_t* g = G + row * GLD;
    const int c0 = lane * 16;

    float cv[16];
    {
        short8 a = *(const short8*)(g + c0);
        short8 b = *(const short8*)(g + c0 + 8);
#pragma unroll
        for (int i = 0; i < 8; ++i) {
            cv[i]     = bf2f((ushort_t)a[i]) + bias_c[c0 + i];
            cv[8 + i] = bf2f((ushort_t)b[i]) + bias_c[c0 + 8 + i];
        }
    }
    float mx = cv[0];
#pragma unroll
    for (int i = 1; i < 16; ++i) mx = fmaxf(mx, cv[i]);
#pragma unroll
    for (int m = 1; m < 64; m <<= 1) mx = fmaxf(mx, __shfl_xor(mx, m));
    float sum = 0.f;
#pragma unroll
    for (int i = 0; i < 16; ++i) { cv[i] = __expf(cv[i] - mx); sum += cv[i]; }
#pragma unroll
    for (int m = 1; m < 64; m <<= 1) sum += __shfl_xor(sum, m);
    const float inv = 1.0f / sum;

    {
        short8 a = *(const short8*)(g + 1024 + c0);
        short8 b = *(const short8*)(g + 1024 + c0 + 8);
        short8 oa, ob;
#pragma unroll
        for (int i = 0; i < 8; ++i) {
            float ha = bf2f((ushort_t)a[i]) + bias_hat[c0 + i];
            float hb = bf2f((ushort_t)b[i]) + bias_hat[c0 + 8 + i];
            oa[i] = (short)f2bf(cv[i] * inv * fmaxf(ha, 0.f));
            ob[i] = (short)f2bf(cv[8 + i] * inv * fmaxf(hb, 0.f));
        }
        *(short8*)(g + c0) = oa;
        *(short8*)(g + c0 + 8) = ob;
    }

    {
        short8 a = *(const short8*)(g + 2048 + c0);
        short8 b = *(const short8*)(g + 2048 + c0 + 8);
        const float* hp = hidden + row * 1024 + c0;
        short8 oa, ob;
#pragma unroll
        for (int i = 0; i < 8; ++i) {
            float ra = 1.0f / (1.0f + __expf(-(bf2f((ushort_t)a[i]) + bias_r[c0 + i])));
            float rb = 1.0f / (1.0f + __expf(-(bf2f((ushort_t)b[i]) + bias_r[c0 + 8 + i])));
            oa[i] = (short)f2bf(ra * hp[i]);
            ob[i] = (short)f2bf(rb * hp[8 + i]);
        }
        ushort_t* rp = rh + row * 1024 + c0;
        *(short8*)rp = oa;
        *(short8*)(rp + 8) = ob;
    }
}

// ---- GEMM2 + fused final epilogue, 64x128 tile for TLP ---------------------
// t6 = rh @ Whh^T; out = (1-z)*tanh(xh + bias_h + t6) + z*hidden + hat
#define CSTRIDE 132
__global__ __launch_bounds__(256) void gemm2_final(
    const ushort_t* __restrict__ A, const ushort_t* __restrict__ B,
    const ushort_t* __restrict__ G, const float* __restrict__ bias_z,
    const float* __restrict__ bias_h, const float* __restrict__ hidden,
    float* __restrict__ out)
{
    const int bn0 = blockIdx.x * 128;
    const int bm0 = blockIdx.y * 64;

    __shared__ ushort_t smem[64 * CSTRIDE];   // 16.5 KiB; K-loop uses first 12 KiB
    ushort_t* As = smem;            // 64 x 32
    ushort_t* Bs = smem + 2048;     // 128 x 32

    const int t = threadIdx.x;
    const int wave = t >> 6, lane = t & 63;
    const int wr = wave >> 1, wcq = wave & 1;    // 2x2 wave grid: 32m x 64n each
    const int q = lane >> 4, r16 = lane & 15;
    const int lrow = lane >> 2;
    const int lcol = (lane & 3) * 8;

    float4v acc[2][4];
#pragma unroll
    for (int i = 0; i < 2; ++i)
#pragma unroll
        for (int j = 0; j < 4; ++j)
            acc[i][j] = {0.f, 0.f, 0.f, 0.f};

    for (int k0 = 0; k0 < 1024; k0 += 32) {
        // 12 chunks of 16 rows (A: 0..3, B: 4..11), 3 per wave
#pragma unroll
        for (int j = 0; j < 3; ++j) {
            int l = wave * 3 + j;
            if (l < 4) {
                const ushort_t* gp = A + (size_t)(bm0 + l * 16 + lrow) * 1024 + k0 + lcol;
                __builtin_amdgcn_global_load_lds(
                    (const __attribute__((address_space(1))) void*)gp,
                    (__attribute__((address_space(3))) void*)(As + l * 512),
                    16, 0, 0);
            } else {
                const ushort_t* gp = B + (size_t)(bn0 + (l - 4) * 16 + lrow) * 1024 + k0 + lcol;
                __builtin_amdgcn_global_load_lds(
                    (const __attribute__((address_space(1))) void*)gp,
                    (__attribute__((address_space(3))) void*)(Bs + (l - 4) * 512),
                    16, 0, 0);
            }
        }
        __syncthreads();

        short8 af[2], bf[4];
#pragma unroll
        for (int mi = 0; mi < 2; ++mi)
            af[mi] = *(const short8*)&As[(wr * 32 + mi * 16 + r16) * 32 + q * 8];
#pragma unroll
        for (int ni = 0; ni < 4; ++ni)
            bf[ni] = *(const short8*)&Bs[(wcq * 64 + ni * 16 + r16) * 32 + q * 8];
#pragma unroll
        for (int mi = 0; mi < 2; ++mi)
#pragma unroll
            for (int ni = 0; ni < 4; ++ni)
                acc[mi][ni] = __builtin_amdgcn_mfma_f32_16x16x32_bf16(
                    af[mi], bf[ni], acc[mi][ni], 0, 0, 0);
        __syncthreads();
    }

    // stage t6 tile to LDS (bf16), then coalesced epilogue
#pragma unroll
    for (int mi = 0; mi < 2; ++mi)
#pragma unroll
        for (int ni = 0; ni < 4; ++ni)
#pragma unroll
            for (int reg = 0; reg < 4; ++reg) {
                int rl = wr * 32 + mi * 16 + q * 4 + reg;
                int cl = wcq * 64 + ni * 16 + r16;
                smem[rl * CSTRIDE + cl] = f2bf(acc[mi][ni][reg]);
            }
    __syncthreads();

    const int colL = t & 127;
    const int gc = bn0 + colL;
    const float bz = bias_z[gc];
    const float bh = bias_h[gc];
    const int rbase = t >> 7;                  // 0 or 1
#pragma unroll 4
    for (int pass = 0; pass < 32; ++pass) {
        const int rowL = pass * 2 + rbase;
        const size_t gr = (size_t)(bm0 + rowL);
        const ushort_t* grow = G + gr * GLD;
        float z = 1.0f / (1.0f + __expf(-(bf2f(grow[3072 + gc]) + bz)));
        float targ = bf2f(grow[4096 + gc]) + bh + bf2f(smem[rowL * CSTRIDE + colL]);
        float th = 1.0f - 2.0f / (__expf(2.0f * targ) + 1.0f);
        out[gr * 1024 + gc] =
            (1.0f - z) * th + z * hidden[gr * 1024 + gc] + bf2f(grow[gc]);
    }
}

// ---- launch ----------------------------------------------------------------

extern "C" void kernel_launch(void* const* d_in, const int* in_sizes, int n_in,
                              void* d_out, int out_size, void* d_ws, size_t ws_size,
                              hipStream_t stream)
{
    const float* x        = (const float*)d_in[0];
    const float* hidden   = (const float*)d_in[1];
    const float* wxr      = (const float*)d_in[2];
    const float* whr      = (const float*)d_in[3];
    const float* bias_r   = (const float*)d_in[4];
    const float* wxz      = (const float*)d_in[5];
    const float* whz      = (const float*)d_in[6];
    const float* bias_z   = (const float*)d_in[7];
    const float* wxh      = (const float*)d_in[8];
    const float* whh      = (const float*)d_in[9];
    const float* bias_h   = (const float*)d_in[10];
    const float* wc       = (const float*)d_in[11];
    const float* bias_c   = (const float*)d_in[12];
    const float* what     = (const float*)d_in[13];
    const float* bias_hat = (const float*)d_in[14];
    float* out = (float*)d_out;

    char* ws = (char*)d_ws;
    ushort_t* G     = (ushort_t*)(ws);                    // [8192,5120] bf16, 80 MiB
    ushort_t* Abf   = (ushort_t*)(ws + 83886080);         // [8192,2048] bf16, 32 MiB
    ushort_t* Wbf   = (ushort_t*)(ws + 117440512);        // [5120,2048] bf16, 20 MiB
    ushort_t* Whhbf = (ushort_t*)(ws + 138412032);        // [1024,1024] bf16,  2 MiB
    ushort_t* rhbf  = (ushort_t*)(ws + 140509184);        // [8192,1024] bf16, 16 MiB

    pack_all<<<27648, 256, 0, stream>>>(x, hidden, wc, what, wxr, whr, wxz, whz,
                                        wxh, whh, Abf, Wbf, Whhbf);

    // GEMM1: G = Abf @ Wbf^T   (M=8192, N=5120, K=2048; xh region K=1024)
    gemm1<<<640, 512, 0, stream>>>(Abf, Wbf, G);

    // fused softmax/hat + rh (wave per row)
    row_pass<<<B_ROWS / 4, 256, 0, stream>>>(G, bias_c, bias_hat, bias_r, hidden, rhbf);

    // GEMM2 + final epilogue -> out
    gemm2_final<<<dim3(8, 128), 256, 0, stream>>>(rhbf, Whhbf, G, bias_z, bias_h,
                                                  hidden, out);
}

// Round 5
// 404.006 us; speedup vs baseline: 1.0057x; 1.0057x over previous
//
#include <hip/hip_runtime.h>

typedef unsigned short ushort_t;
typedef __attribute__((ext_vector_type(8))) short short8;
typedef __attribute__((ext_vector_type(4))) float float4v;
typedef __attribute__((ext_vector_type(4))) ushort_t ushort4v;

#define B_ROWS 8192
#define HDIM   1024
#define GLD    5120   // G cols: [hat(c) | hat_raw | r | z | xh]

__device__ __forceinline__ float bf2f(ushort_t u) {
    return __uint_as_float(((unsigned)u) << 16);
}
__device__ __forceinline__ ushort_t f2bf(float f) {
    unsigned u = __float_as_uint(f);
    u += 0x7FFFu + ((u >> 16) & 1u);   // round-to-nearest-even
    return (ushort_t)(u >> 16);
}

// ---- one pack kernel for A, W, Whh ----------------------------------------
__global__ __launch_bounds__(256) void pack_all(
    const float* __restrict__ x, const float* __restrict__ h,
    const float* __restrict__ wc, const float* __restrict__ what,
    const float* __restrict__ wxr, const float* __restrict__ whr,
    const float* __restrict__ wxz, const float* __restrict__ whz,
    const float* __restrict__ wxh, const float* __restrict__ whh,
    ushort_t* __restrict__ A, ushort_t* __restrict__ W,
    ushort_t* __restrict__ Whh)
{
    const int bid = blockIdx.x;
    float4v v;
    ushort_t* dst;
    size_t i4;
    if (bid < 16384) {                       // ---- A = [x | hidden]
        i4 = ((size_t)bid * 256 + threadIdx.x) * 4;
        int c = (int)(i4 & 2047);
        size_t b = i4 >> 11;
        const float* src = (c < 1024) ? (x + b * 1024 + c)
                                      : (h + b * 1024 + (c - 1024));
        v = *(const float4v*)src;
        dst = A + i4;
    } else if (bid < 26624) {                // ---- W rows: wc|what|[xr|hr]|[xz|hz]|[xh|junk]
        i4 = ((size_t)(bid - 16384) * 256 + threadIdx.x) * 4;
        int j = (int)(i4 >> 11);
        int k = (int)(i4 & 2047);
        int r = j >> 10, jr = j & 1023;
        if (r == 0) {
            v = *(const float4v*)(wc + (size_t)j * 2048 + k);
        } else if (r == 1) {
            v = *(const float4v*)(what + (size_t)jr * 2048 + k);
        } else if (r == 4) {
            v = (k < 1024) ? *(const float4v*)(wxh + (size_t)jr * 1024 + k)
                           : (float4v){0.f, 0.f, 0.f, 0.f};
        } else {
            const float* p0 = (r == 2) ? wxr : wxz;
            const float* p1 = (r == 2) ? whr : whz;
            const float* p = (k < 1024) ? (p0 + (size_t)jr * 1024 + k)
                                        : (p1 + (size_t)jr * 1024 + (k - 1024));
            v = *(const float4v*)p;
        }
        dst = W + i4;
    } else {                                 // ---- Whh
        i4 = ((size_t)(bid - 26624) * 256 + threadIdx.x) * 4;
        v = *(const float4v*)(whh + i4);
        dst = Whh + i4;
    }
    ushort4v o;
#pragma unroll
    for (int t = 0; t < 4; ++t) o[t] = f2bf(v[t]);
    *(ushort4v*)dst = o;
}

// ---- GEMM1: G = A @ W^T -----------------------------------------------------
// R4's verified-correct schedule (passed on HW), register-dieted to kill the
// spill R4's counters exposed (+47MB WRITE = scratch):
//  * 8 named ds_read bases ({A,B}x{S0,S1}x{kh0,kh1}); H*8192+mi*1024 folds
//    into the 16-bit ds offset imm (<= 22528B) -> nothing for LICM to hoist.
//  * stage offsets: only aO0/bO0 live; +16384-elem row-group delta and
//    H/KT terms are compile-time or scalar adds (transient).
// Structure: 256x256 tile, BK=64, 8 waves, quadrant 8-phase, ONE barrier per
// phase, DS/MFMA overlap inside the phase:
//   phase = {vmcnt(N); lgkmcnt(0); barrier; stage; ds_reads(P+1); MFMA(P)}
// lgkm(0) BEFORE barrier => WAR-safe stages; vmcnt(N) BEFORE barrier =>
// RAW-safe reads. Frag banks: A0->fX, A1->fY; B bank = half XOR tileparity.
// Zero-conflict LDS pattern (R2-verified, SQ_LDS_BANK_CONFLICT=0):
// LDS chunk c of row r holds global chunk c^(r&7).
// Waits: P2:vm6 P3:vm6 P4:vm4 P6:vm6 P7:vm6 P8:vm4; P1,P5 none.

#define GLOAD(gp, lp) __builtin_amdgcn_global_load_lds( \
    (const __attribute__((address_space(1))) void*)(gp), \
    (__attribute__((address_space(3))) void*)(lp), 16, 0, 0)

#define BARRIER do { __builtin_amdgcn_s_barrier(); \
    __builtin_amdgcn_sched_barrier(0); } while (0)
#define WLG do { \
    asm volatile("s_waitcnt lgkmcnt(0)" ::: "memory"); \
    __builtin_amdgcn_sched_barrier(0); } while (0)
#define WVM6 do { \
    asm volatile("s_waitcnt vmcnt(6)" ::: "memory"); \
    __builtin_amdgcn_sched_barrier(0); } while (0)
#define WVM4 do { \
    asm volatile("s_waitcnt vmcnt(4)" ::: "memory"); \
    __builtin_amdgcn_sched_barrier(0); } while (0)
#define WVM2 do { \
    asm volatile("s_waitcnt vmcnt(2)" ::: "memory"); \
    __builtin_amdgcn_sched_barrier(0); } while (0)
#define WVM0 do { \
    asm volatile("s_waitcnt vmcnt(0)" ::: "memory"); \
    __builtin_amdgcn_sched_barrier(0); } while (0)

// stage one 128x64 half-tile: 8 waves x 2 GLOADs x 1KB = 16KB
#define STAGE_A(S, H, KT) do { \
    GLOAD(A + (aO0 + (H) * 262144u + (unsigned)(KT) * 64u), \
          dstA + (S) * 32768 + (H) * 8192); \
    GLOAD(A + (aO0 + 16384u + (H) * 262144u + (unsigned)(KT) * 64u), \
          dstA + (S) * 32768 + (H) * 8192 + 512); } while (0)
#define STAGE_B(S, H, KT) do { \
    GLOAD(B + (bO0 + (H) * 262144u + (unsigned)(KT) * 64u), \
          dstB + (S) * 32768 + (H) * 8192); \
    GLOAD(B + (bO0 + 16384u + (H) * 262144u + (unsigned)(KT) * 64u), \
          dstB + (S) * 32768 + (H) * 8192 + 512); } while (0)

// 8 ds_read_b128: A-fragments (both kh) of one A-half into bank BK
#define RD_A(BK, S, H) do { \
    _Pragma("unroll") \
    for (int mi = 0; mi < 4; ++mi) { \
        BK[mi]     = *(const short8*)(lds + ((S) ? aS1k0 : aS0k0) + (H) * 8192 + mi * 1024); \
        BK[4 + mi] = *(const short8*)(lds + ((S) ? aS1k1 : aS0k1) + (H) * 8192 + mi * 1024); } } while (0)

// 4 ds_read_b128: A-fragments of one kh only
#define RD_A_KH(BK, S, H, KH) do { \
    _Pragma("unroll") \
    for (int mi = 0; mi < 4; ++mi) \
        BK[(KH) * 4 + mi] = *(const short8*)(lds + \
            ((KH) ? ((S) ? aS1k1 : aS0k1) : ((S) ? aS1k0 : aS0k0)) + \
            (H) * 8192 + mi * 1024); } while (0)

// 4 ds_read_b128: B-fragments (both kh) of one B-half into bank BK
#define RD_B(BK, S, H) do { \
    _Pragma("unroll") \
    for (int ni = 0; ni < 2; ++ni) { \
        BK[ni]     = *(const short8*)(lds + ((S) ? bS1k0 : bS0k0) + (H) * 8192 + ni * 1024); \
        BK[2 + ni] = *(const short8*)(lds + ((S) ? bS1k1 : bS0k1) + (H) * 8192 + ni * 1024); } } while (0)

// 16 MFMA: one quadrant (HA,HB), both kh, from banks AB/BB
#define MM(HA, HB, AB, BB) do { \
    __builtin_amdgcn_s_setprio(1); \
    _Pragma("unroll") \
    for (int mi = 0; mi < 4; ++mi) { \
        _Pragma("unroll") \
        for (int ni = 0; ni < 2; ++ni) { \
            acc[HA][HB][mi][ni] = __builtin_amdgcn_mfma_f32_16x16x32_bf16( \
                AB[mi], BB[ni], acc[HA][HB][mi][ni], 0, 0, 0); \
            acc[HA][HB][mi][ni] = __builtin_amdgcn_mfma_f32_16x16x32_bf16( \
                AB[4 + mi], BB[2 + ni], acc[HA][HB][mi][ni], 0, 0, 0); } } \
    __builtin_amdgcn_s_setprio(0); } while (0)

__global__ __launch_bounds__(512, 2) void gemm1(
    const ushort_t* __restrict__ A, const ushort_t* __restrict__ B,
    ushort_t* __restrict__ C)
{
    // heavy blocks (K=2048) first, light (K=1024) last; XCD-striped within each
    const int bid = blockIdx.x;
    int bx, by;
    if (bid < 512) { int hI = (bid & 7) * 64 + (bid >> 3); by = hI >> 4; bx = hI & 15; }
    else           { int b = bid - 512; int lI = (b & 7) * 16 + (b >> 3); by = lI >> 2; bx = 16 + (lI & 3); }
    const int bn0 = bx * 256;
    const int bm0 = by * 256;
    const int K = (bx >= 16) ? 1024 : 2048;
    const int NIT = K >> 7;                      // 2 K-tiles (128 k) per iter

    __shared__ ushort_t lds[65536];              // 128 KiB
    // element offsets: A(s,h) = s*32768 + h*8192 ; B(s,h) = s*32768 + 16384 + h*8192

    const int t = threadIdx.x;
    const int w = t >> 6, lane = t & 63;
    const int q = lane >> 4, r16 = lane & 15;

    // ---- ds_read bases: 8 named regs; H/mi fold into ds offset imm ----
    const int c0 = ((q ^ (r16 & 7)) << 3);           // kh0 chunk
    const int c1 = (((4 + q) ^ (r16 & 7)) << 3);     // kh1 chunk
    const int arow = ((w >> 2) * 64 + r16) * 64;
    const int brow = ((w & 3) * 32 + r16) * 64;
    const int aS0k0 = arow + c0;
    const int aS0k1 = arow + c1;
    const int aS1k0 = arow + c0 + 32768;
    const int aS1k1 = arow + c1 + 32768;
    const int bS0k0 = 16384 + brow + c0;
    const int bS0k1 = 16384 + brow + c1;
    const int bS1k0 = 49152 + brow + c0;
    const int bS1k1 = 49152 + brow + c1;

    // ---- staging: lane l of wave w writes row w*16+(l>>3), chunk (l&7)^(l>>3)
    const unsigned srow0 = (unsigned)(w * 16 + ((lane >> 3) & 7));
    const unsigned kcO = (unsigned)(((lane & 7) ^ (lane >> 3)) << 3);
    const unsigned aO0 = ((unsigned)bm0 + srow0) * 2048u + kcO;
    const unsigned bO0 = ((unsigned)bn0 + srow0) * 2048u + kcO;
    ushort_t* dstA = lds + w * 1024;
    ushort_t* dstB = lds + 16384 + w * 1024;

    float4v acc[2][2][4][2];
#pragma unroll
    for (int i = 0; i < 2; ++i)
#pragma unroll
        for (int j = 0; j < 2; ++j)
#pragma unroll
            for (int m = 0; m < 4; ++m)
#pragma unroll
                for (int n = 0; n < 2; ++n)
                    acc[i][j][m][n] = {0.f, 0.f, 0.f, 0.f};

    short8 fX[8], fY[8];         // A banks: X = A-half0, Y = A-half1
    short8 gA[4], gB[4];         // B banks: E: B0->gA,B1->gB ; O: B0->gB,B1->gA

    // ---- prologue: stage E0 fully + A(s1,0)@O0 + B(s1,1)@O0, then pre-read
    STAGE_A(0, 0, 0);
    STAGE_B(0, 1, 0);
    STAGE_B(0, 0, 0);
    STAGE_A(0, 1, 0);
    STAGE_A(1, 0, 1);
    STAGE_B(1, 1, 1);
    WVM4;               // E0's 4 halves landed (last 2 stages stay in flight)
    BARRIER;
    RD_A(fX, 0, 0);     // A0@E0 -> X
    RD_B(gA, 0, 0);     // B0@E0 -> alpha

    // ---- main loop: iterations 0..NIT-2, last peeled ----
#pragma unroll 1
    for (int it = 0; it < NIT - 1; ++it) {
        const int kO  = 2 * it + 1;
        const int kE2 = 2 * it + 2;
        const int kO2 = 2 * it + 3;
        // P1: MFMA E(A0,B0)=X*gA | stage B(s1,0)@O | read gB=B(s0,1)
        WLG; BARRIER;
        STAGE_B(1, 0, kO);
        RD_B(gB, 0, 1);
        MM(0, 0, fX, gA);
        // P2: MFMA E(A0,B1)=X*gB | stage A(s1,1)@O | read fY=A(s0,1)
        WVM6; WLG; BARRIER;
        STAGE_A(1, 1, kO);
        RD_A(fY, 0, 1);
        MM(0, 1, fX, gB);
        // P3: MFMA E(A1,B1)=Y*gB | stage A(s0,0)@E' | read fX kh0 = A(s1,0)
        WVM6; WLG; BARRIER;
        STAGE_A(0, 0, kE2);
        RD_A_KH(fX, 1, 0, 0);
        MM(1, 1, fY, gB);
        // P4: MFMA E(A1,B0)=Y*gA | stage B(s0,1)@E' | read fX kh1, gB=B(s1,0)
        WVM4; WLG; BARRIER;
        STAGE_B(0, 1, kE2);
        RD_A_KH(fX, 1, 0, 1);
        RD_B(gB, 1, 0);
        MM(1, 0, fY, gA);
        // P5: MFMA O(A0,B0)=X*gB | stage B(s0,0)@E' | read gA=B(s1,1)
        WLG; BARRIER;
        STAGE_B(0, 0, kE2);
        RD_B(gA, 1, 1);
        MM(0, 0, fX, gB);
        // P6: MFMA O(A0,B1)=X*gA | stage A(s0,1)@E' | read fY=A(s1,1)
        WVM6; WLG; BARRIER;
        STAGE_A(0, 1, kE2);
        RD_A(fY, 1, 1);
        MM(0, 1, fX, gA);
        // P7: MFMA O(A1,B1)=Y*gA | stage A(s1,0)@O' | read fX' kh0 = A(s0,0)@E'
        WVM6; WLG; BARRIER;
        STAGE_A(1, 0, kO2);
        RD_A_KH(fX, 0, 0, 0);
        MM(1, 1, fY, gA);
        // P8: MFMA O(A1,B0)=Y*gB | stage B(s1,1)@O' | read fX' kh1, gA'=B(s0,0)@E'
        WVM4; WLG; BARRIER;
        STAGE_B(1, 1, kO2);
        RD_A_KH(fX, 0, 0, 1);
        RD_B(gA, 0, 0);
        MM(1, 0, fY, gB);
    }

    // ---- peeled last iteration (E fully staged; O needs B(s1,0), A(s1,1)) ----
    {
        const int kO = 2 * (NIT - 1) + 1;
        // pP1
        WLG; BARRIER;
        STAGE_B(1, 0, kO);
        RD_B(gB, 0, 1);
        MM(0, 0, fX, gA);
        // pP2
        WVM6; WLG; BARRIER;
        STAGE_A(1, 1, kO);
        RD_A(fY, 0, 1);
        MM(0, 1, fX, gB);
        // pP3
        WVM6; WLG; BARRIER;
        RD_A_KH(fX, 1, 0, 0);
        MM(1, 1, fY, gB);
        // pP4
        WVM2; WLG; BARRIER;
        RD_A_KH(fX, 1, 0, 1);
        RD_B(gB, 1, 0);
        MM(1, 0, fY, gA);
        // pP5
        WLG; BARRIER;
        RD_B(gA, 1, 1);
        MM(0, 0, fX, gB);
        // pP6
        WVM0; WLG; BARRIER;
        RD_A(fY, 1, 1);
        MM(0, 1, fX, gA);
        // pP7
        WLG; BARRIER;
        MM(1, 1, fY, gA);
        // pP8
        WLG; BARRIER;
        MM(1, 0, fY, gB);
    }

    // C/D layout: col = lane&15, row = (lane>>4)*4 + reg  [m89/m91]
    {
        const int wm2 = w >> 2, wn2 = w & 3;
#pragma unroll
        for (int ha = 0; ha < 2; ++ha)
#pragma unroll
            for (int hb = 0; hb < 2; ++hb)
#pragma unroll
                for (int mi = 0; mi < 4; ++mi)
#pragma unroll
                    for (int ni = 0; ni < 2; ++ni)
#pragma unroll
                        for (int reg = 0; reg < 4; ++reg) {
                            int row = bm0 + ha * 128 + wm2 * 64 + mi * 16 + q * 4 + reg;
                            int col = bn0 + hb * 128 + wn2 * 32 + ni * 16 + r16;
                            C[(size_t)row * GLD + col] = f2bf(acc[ha][hb][mi][ni][reg]);
                        }
    }
}

// ---- fused row pass: softmax*relu (hat) + rh, wave-per-row, no syncs -------
__global__ __launch_bounds__(256) void row_pass(
    ushort_t* __restrict__ G, const float* __restrict__ bias_c,
    const float* __restrict__ bias_hat, const float* __restrict__ bias_r,
    const float* __restrict__ hidden, ushort_t* __restrict__ rh)
{
    const int wave = threadIdx.x >> 6, lane = threadIdx.x & 63;
    const size_t row = (size_t)blockIdx.x * 4 + wave;
    ushort_t* g = G + row * GLD;
    const int c0 = lane * 16;

    float cv[16];
    {
        short8 a = *(const short8*)(g + c0);
        short8 b = *(const short8*)(g + c0 + 8);
#pragma unroll
        for (int i = 0; i < 8; ++i) {
            cv[i]     = bf2f((ushort_t)a[i]) + bias_c[c0 + i];
            cv[8 + i] = bf2f((ushort_t)b[i]) + bias_c[c0 + 8 + i];
        }
    }
    float mx = cv[0];
#pragma unroll
    for (int i = 1; i < 16; ++i) mx = fmaxf(mx, cv[i]);
#pragma unroll
    for (int m = 1; m < 64; m <<= 1) mx = fmaxf(mx, __shfl_xor(mx, m));
    float sum = 0.f;
#pragma unroll
    for (int i = 0; i < 16; ++i) { cv[i] = __expf(cv[i] - mx); sum += cv[i]; }
#pragma unroll
    for (int m = 1; m < 64; m <<= 1) sum += __shfl_xor(sum, m);
    const float inv = 1.0f / sum;

    {
        short8 a = *(const short8*)(g + 1024 + c0);
        short8 b = *(const short8*)(g + 1024 + c0 + 8);
        short8 oa, ob;
#pragma unroll
        for (int i = 0; i < 8; ++i) {
            float ha = bf2f((ushort_t)a[i]) + bias_hat[c0 + i];
            float hb = bf2f((ushort_t)b[i]) + bias_hat[c0 + 8 + i];
            oa[i] = (short)f2bf(cv[i] * inv * fmaxf(ha, 0.f));
            ob[i] = (short)f2bf(cv[8 + i] * inv * fmaxf(hb, 0.f));
        }
        *(short8*)(g + c0) = oa;
        *(short8*)(g + c0 + 8) = ob;
    }

    {
        short8 a = *(const short8*)(g + 2048 + c0);
        short8 b = *(const short8*)(g + 2048 + c0 + 8);
        const float* hp = hidden + row * 1024 + c0;
        short8 oa, ob;
#pragma unroll
        for (int i = 0; i < 8; ++i) {
            float ra = 1.0f / (1.0f + __expf(-(bf2f((ushort_t)a[i]) + bias_r[c0 + i])));
            float rb = 1.0f / (1.0f + __expf(-(bf2f((ushort_t)b[i]) + bias_r[c0 + 8 + i])));
            oa[i] = (short)f2bf(ra * hp[i]);
            ob[i] = (short)f2bf(rb * hp[8 + i]);
        }
        ushort_t* rp = rh + row * 1024 + c0;
        *(short8*)rp = oa;
        *(short8*)(rp + 8) = ob;
    }
}

// ---- GEMM2 + fused final epilogue, 64x128 tile for TLP ---------------------
// t6 = rh @ Whh^T; out = (1-z)*tanh(xh + bias_h + t6) + z*hidden + hat
#define CSTRIDE 132
__global__ __launch_bounds__(256) void gemm2_final(
    const ushort_t* __restrict__ A, const ushort_t* __restrict__ B,
    const ushort_t* __restrict__ G, const float* __restrict__ bias_z,
    const float* __restrict__ bias_h, const float* __restrict__ hidden,
    float* __restrict__ out)
{
    const int bn0 = blockIdx.x * 128;
    const int bm0 = blockIdx.y * 64;

    __shared__ ushort_t smem[64 * CSTRIDE];   // 16.5 KiB; K-loop uses first 12 KiB
    ushort_t* As = smem;            // 64 x 32
    ushort_t* Bs = smem + 2048;     // 128 x 32

    const int t = threadIdx.x;
    const int wave = t >> 6, lane = t & 63;
    const int wr = wave >> 1, wcq = wave & 1;    // 2x2 wave grid: 32m x 64n each
    const int q = lane >> 4, r16 = lane & 15;
    const int lrow = lane >> 2;
    const int lcol = (lane & 3) * 8;

    float4v acc[2][4];
#pragma unroll
    for (int i = 0; i < 2; ++i)
#pragma unroll
        for (int j = 0; j < 4; ++j)
            acc[i][j] = {0.f, 0.f, 0.f, 0.f};

    for (int k0 = 0; k0 < 1024; k0 += 32) {
        // 12 chunks of 16 rows (A: 0..3, B: 4..11), 3 per wave
#pragma unroll
        for (int j = 0; j < 3; ++j) {
            int l = wave * 3 + j;
            if (l < 4) {
                const ushort_t* gp = A + (size_t)(bm0 + l * 16 + lrow) * 1024 + k0 + lcol;
                __builtin_amdgcn_global_load_lds(
                    (const __attribute__((address_space(1))) void*)gp,
                    (__attribute__((address_space(3))) void*)(As + l * 512),
                    16, 0, 0);
            } else {
                const ushort_t* gp = B + (size_t)(bn0 + (l - 4) * 16 + lrow) * 1024 + k0 + lcol;
                __builtin_amdgcn_global_load_lds(
                    (const __attribute__((address_space(1))) void*)gp,
                    (__attribute__((address_space(3))) void*)(Bs + (l - 4) * 512),
                    16, 0, 0);
            }
        }
        __syncthreads();

        short8 af[2], bf[4];
#pragma unroll
        for (int mi = 0; mi < 2; ++mi)
            af[mi] = *(const short8*)&As[(wr * 32 + mi * 16 + r16) * 32 + q * 8];
#pragma unroll
        for (int ni = 0; ni < 4; ++ni)
            bf[ni] = *(const short8*)&Bs[(wcq * 64 + ni * 16 + r16) * 32 + q * 8];
#pragma unroll
        for (int mi = 0; mi < 2; ++mi)
#pragma unroll
            for (int ni = 0; ni < 4; ++ni)
                acc[mi][ni] = __builtin_amdgcn_mfma_f32_16x16x32_bf16(
                    af[mi], bf[ni], acc[mi][ni], 0, 0, 0);
        __syncthreads();
    }

    // stage t6 tile to LDS (bf16), then coalesced epilogue
#pragma unroll
    for (int mi = 0; mi < 2; ++mi)
#pragma unroll
        for (int ni = 0; ni < 4; ++ni)
#pragma unroll
            for (int reg = 0; reg < 4; ++reg) {
                int rl = wr * 32 + mi * 16 + q * 4 + reg;
                int cl = wcq * 64 + ni * 16 + r16;
                smem[rl * CSTRIDE + cl] = f2bf(acc[mi][ni][reg]);
            }
    __syncthreads();

    const int colL = t & 127;
    const int gc = bn0 + colL;
    const float bz = bias_z[gc];
    const float bh = bias_h[gc];
    const int rbase = t >> 7;                  // 0 or 1
#pragma unroll 4
    for (int pass = 0; pass < 32; ++pass) {
        const int rowL = pass * 2 + rbase;
        const size_t gr = (size_t)(bm0 + rowL);
        const ushort_t* grow = G + gr * GLD;
        float z = 1.0f / (1.0f + __expf(-(bf2f(grow[3072 + gc]) + bz)));
        float targ = bf2f(grow[4096 + gc]) + bh + bf2f(smem[rowL * CSTRIDE + colL]);
        float th = 1.0f - 2.0f / (__expf(2.0f * targ) + 1.0f);
        out[gr * 1024 + gc] =
            (1.0f - z) * th + z * hidden[gr * 1024 + gc] + bf2f(grow[gc]);
    }
}

// ---- launch ----------------------------------------------------------------

extern "C" void kernel_launch(void* const* d_in, const int* in_sizes, int n_in,
                              void* d_out, int out_size, void* d_ws, size_t ws_size,
                              hipStream_t stream)
{
    const float* x        = (const float*)d_in[0];
    const float* hidden   = (const float*)d_in[1];
    const float* wxr      = (const float*)d_in[2];
    const float* whr      = (const float*)d_in[3];
    const float* bias_r   = (const float*)d_in[4];
    const float* wxz      = (const float*)d_in[5];
    const float* whz      = (const float*)d_in[6];
    const float* bias_z   = (const float*)d_in[7];
    const float* wxh      = (const float*)d_in[8];
    const float* whh      = (const float*)d_in[9];
    const float* bias_h   = (const float*)d_in[10];
    const float* wc       = (const float*)d_in[11];
    const float* bias_c   = (const float*)d_in[12];
    const float* what     = (const float*)d_in[13];
    const float* bias_hat = (const float*)d_in[14];
    float* out = (float*)d_out;

    char* ws = (char*)d_ws;
    ushort_t* G     = (ushort_t*)(ws);                    // [8192,5120] bf16, 80 MiB
    ushort_t* Abf   = (ushort_t*)(ws + 83886080);         // [8192,2048] bf16, 32 MiB
    ushort_t* Wbf   = (ushort_t*)(ws + 117440512);        // [5120,2048] bf16, 20 MiB
    ushort_t* Whhbf = (ushort_t*)(ws + 138412032);        // [1024,1024] bf16,  2 MiB
    ushort_t* rhbf  = (ushort_t*)(ws + 140509184);        // [8192,1024] bf16, 16 MiB

    pack_all<<<27648, 256, 0, stream>>>(x, hidden, wc, what, wxr, whr, wxz, whz,
                                        wxh, whh, Abf, Wbf, Whhbf);

    // GEMM1: G = Abf @ Wbf^T   (M=8192, N=5120, K=2048; xh region K=1024)
    gemm1<<<640, 512, 0, stream>>>(Abf, Wbf, G);

    // fused softmax/hat + rh (wave per row)
    row_pass<<<B_ROWS / 4, 256, 0, stream>>>(G, bias_c, bias_hat, bias_r, hidden, rhbf);

    // GEMM2 + final epilogue -> out
    gemm2_final<<<dim3(8, 128), 256, 0, stream>>>(rhbf, Whhbf, G, bias_z, bias_h,
                                                  hidden, out);
}

// Round 7
// 363.092 us; speedup vs baseline: 1.1190x; 1.1127x over previous
//
#include <hip/hip_runtime.h>

typedef unsigned short ushort_t;
typedef __attribute__((ext_vector_type(8))) short short8;
typedef __attribute__((ext_vector_type(4))) float float4v;
typedef __attribute__((ext_vector_type(4))) ushort_t ushort4v;

#define B_ROWS 8192
#define HDIM   1024
#define GLD    5120   // G cols: [hat(c) | hat_raw | r | z | xh]

__device__ __forceinline__ float bf2f(ushort_t u) {
    return __uint_as_float(((unsigned)u) << 16);
}
__device__ __forceinline__ ushort_t f2bf(float f) {
    unsigned u = __float_as_uint(f);
    u += 0x7FFFu + ((u >> 16) & 1u);   // round-to-nearest-even
    return (ushort_t)(u >> 16);
}

// ---- one pack kernel for A, W, Whh ----------------------------------------
__global__ __launch_bounds__(256) void pack_all(
    const float* __restrict__ x, const float* __restrict__ h,
    const float* __restrict__ wc, const float* __restrict__ what,
    const float* __restrict__ wxr, const float* __restrict__ whr,
    const float* __restrict__ wxz, const float* __restrict__ whz,
    const float* __restrict__ wxh, const float* __restrict__ whh,
    ushort_t* __restrict__ A, ushort_t* __restrict__ W,
    ushort_t* __restrict__ Whh)
{
    const int bid = blockIdx.x;
    float4v v;
    ushort_t* dst;
    size_t i4;
    if (bid < 16384) {                       // ---- A = [x | hidden]
        i4 = ((size_t)bid * 256 + threadIdx.x) * 4;
        int c = (int)(i4 & 2047);
        size_t b = i4 >> 11;
        const float* src = (c < 1024) ? (x + b * 1024 + c)
                                      : (h + b * 1024 + (c - 1024));
        v = *(const float4v*)src;
        dst = A + i4;
    } else if (bid < 26624) {                // ---- W rows: wc|what|[xr|hr]|[xz|hz]|[xh|junk]
        i4 = ((size_t)(bid - 16384) * 256 + threadIdx.x) * 4;
        int j = (int)(i4 >> 11);
        int k = (int)(i4 & 2047);
        int r = j >> 10, jr = j & 1023;
        if (r == 0) {
            v = *(const float4v*)(wc + (size_t)j * 2048 + k);
        } else if (r == 1) {
            v = *(const float4v*)(what + (size_t)jr * 2048 + k);
        } else if (r == 4) {
            v = (k < 1024) ? *(const float4v*)(wxh + (size_t)jr * 1024 + k)
                           : (float4v){0.f, 0.f, 0.f, 0.f};
        } else {
            const float* p0 = (r == 2) ? wxr : wxz;
            const float* p1 = (r == 2) ? whr : whz;
            const float* p = (k < 1024) ? (p0 + (size_t)jr * 1024 + k)
                                        : (p1 + (size_t)jr * 1024 + (k - 1024));
            v = *(const float4v*)p;
        }
        dst = W + i4;
    } else {                                 // ---- Whh
        i4 = ((size_t)(bid - 26624) * 256 + threadIdx.x) * 4;
        v = *(const float4v*)(whh + i4);
        dst = Whh + i4;
    }
    ushort4v o;
#pragma unroll
    for (int t = 0; t < 4; ++t) o[t] = f2bf(v[t]);
    *(ushort4v*)dst = o;
}

// ---- GEMM1: G = A @ W^T -----------------------------------------------------
// kh-split 16-phase schedule: 256x256 tile, BK=64, 8 waves, ONE barrier/phase.
// Phase = {vmcnt(N); lgkm(0); barrier; [stage]; 8 MFMA; 2-4 ds_reads for P+1}.
// Frag banks HALVED vs R4/R5 (the spill cause): X[4],Y[4] A-banks + U[2],V[2]
// B-banks = 48 VGPRs. Reads placed AFTER the MFMA cluster so U/V can be
// refilled in the same phase their old content is last used.
// Per-tile phase order: (A0B0)(A0B1)(A1B1)(A1B0) x {k0 then k1}.
// Banks per phase p1..p8: (X,U)(X,V)(Y,V)(Y,U)(X,U)(X,V)(Y,V)(Y,U);
// reads: p1:V<-B1k0 p2:Y<-A1k0 p3:X<-A0k1 p4:U<-B0k1 p5:V<-B1k1 p6:Y<-A1k1
//        p7:X<-A0'k0(next tile) p8:U<-B0'k0(next tile).
// Stages front-loaded P1-P8 (1/phase): P1:A(s1,0) P2:B(s1,0) P3:B(s1,1)
// P4:A(s1,1) P5:A(s0,0)@E' P6:B(s0,0) P7:B(s0,1) P8:A(s0,1). Every buffer
// >=6 phases in flight (>>900cyc HBM); WAR gaps >=1 barrier (verified).
// vmcnt ledger (2 loads/stage, in-order): P1,P2:vm2; P7,P8,P9:vm10; P10:vm8;
// P15:vm6; P16:vm4; others none. Peel: P7:vm6 P8:vm4 P9:vm2 P10:vm0.
// LDS: 8 half-buffers [128 rows][64 k] (128B rows), zero-conflict XOR pattern
// (R2-verified, SQ_LDS_BANK_CONFLICT=0): LDS chunk c of row r = global chunk
// c^(r&7); pre-swizzled global source, linear LDS dest.
// [R6 resubmission: full vmcnt/WAR/bounds/deadlock audit clean; prior
//  failure attributed to infra (R3 precedent: same family passed as R4).]

#define GLOAD(gp, lp) __builtin_amdgcn_global_load_lds( \
    (const __attribute__((address_space(1))) void*)(gp), \
    (__attribute__((address_space(3))) void*)(lp), 16, 0, 0)

#define BARRIER do { __builtin_amdgcn_s_barrier(); \
    __builtin_amdgcn_sched_barrier(0); } while (0)
#define WLG do { \
    asm volatile("s_waitcnt lgkmcnt(0)" ::: "memory"); \
    __builtin_amdgcn_sched_barrier(0); } while (0)
#define WVM(N) do { \
    asm volatile("s_waitcnt vmcnt(" #N ")" ::: "memory"); \
    __builtin_amdgcn_sched_barrier(0); } while (0)

// stage one 128x64 half-tile: 8 waves x 2 GLOADs x 1KB = 16KB
#define STAGE_A(S, H, KT) do { \
    GLOAD(A + (aO0 + (H) * 262144u + (unsigned)(KT) * 64u), \
          dstA + (S) * 32768 + (H) * 8192); \
    GLOAD(A + (aO0 + 16384u + (H) * 262144u + (unsigned)(KT) * 64u), \
          dstA + (S) * 32768 + (H) * 8192 + 512); } while (0)
#define STAGE_B(S, H, KT) do { \
    GLOAD(B + (bO0 + (H) * 262144u + (unsigned)(KT) * 64u), \
          dstB + (S) * 32768 + (H) * 8192); \
    GLOAD(B + (bO0 + 16384u + (H) * 262144u + (unsigned)(KT) * 64u), \
          dstB + (S) * 32768 + (H) * 8192 + 512); } while (0)

// 4 ds_read_b128: one (A-half, kh) set into bank BK
#define RD_A4(BK, S, H, KH) do { \
    _Pragma("unroll") \
    for (int mi = 0; mi < 4; ++mi) \
        BK[mi] = *(const short8*)(lds + (S) * 32768 + (H) * 8192 + mi * 1024 \
                                  + ((KH) ? Ard1 : Ard0)); } while (0)

// 2 ds_read_b128: one (B-half, kh) set into bank BK
#define RD_B2(BK, S, H, KH) do { \
    _Pragma("unroll") \
    for (int ni = 0; ni < 2; ++ni) \
        BK[ni] = *(const short8*)(lds + 16384 + (S) * 32768 + (H) * 8192 + ni * 1024 \
                                  + ((KH) ? Brd1 : Brd0)); } while (0)

// 8 MFMA: one (quadrant, kh) cell
#define MM8(HA, HB, AB, BB) do { \
    __builtin_amdgcn_s_setprio(1); \
    _Pragma("unroll") \
    for (int mi = 0; mi < 4; ++mi) { \
        _Pragma("unroll") \
        for (int ni = 0; ni < 2; ++ni) \
            acc[HA][HB][mi][ni] = __builtin_amdgcn_mfma_f32_16x16x32_bf16( \
                AB[mi], BB[ni], acc[HA][HB][mi][ni], 0, 0, 0); } \
    __builtin_amdgcn_s_setprio(0); } while (0)

__global__ __launch_bounds__(512, 2) void gemm1(
    const ushort_t* __restrict__ A, const ushort_t* __restrict__ B,
    ushort_t* __restrict__ C)
{
    // heavy blocks (K=2048) first, light (K=1024) last; XCD-striped within each
    const int bid = blockIdx.x;
    int bx, by;
    if (bid < 512) { int hI = (bid & 7) * 64 + (bid >> 3); by = hI >> 4; bx = hI & 15; }
    else           { int b = bid - 512; int lI = (b & 7) * 16 + (b >> 3); by = lI >> 2; bx = 16 + (lI & 3); }
    const int bn0 = bx * 256;
    const int bm0 = by * 256;
    const int K = (bx >= 16) ? 1024 : 2048;
    const int NIT = K >> 7;                      // 2 K-tiles (128 k) per iter

    __shared__ ushort_t lds[65536];              // 128 KiB
    // element offsets: A(s,h) = s*32768 + h*8192 ; B(s,h) = 16384 + s*32768 + h*8192

    const int t = threadIdx.x;
    const int w = t >> 6, lane = t & 63;
    const int q = lane >> 4, r16 = lane & 15;

    // ---- ds_read bases (4 live VGPRs; S/H/mi fold into ds offset imm <=58KB)
    const int c0 = ((q ^ (r16 & 7)) << 3);           // kh0 chunk
    const int c1 = (((4 + q) ^ (r16 & 7)) << 3);     // kh1 chunk
    const int Ard0 = ((w >> 2) * 64 + r16) * 64 + c0;
    const int Ard1 = ((w >> 2) * 64 + r16) * 64 + c1;
    const int Brd0 = ((w & 3) * 32 + r16) * 64 + c0;
    const int Brd1 = ((w & 3) * 32 + r16) * 64 + c1;

    // ---- staging: lane l of wave w writes row w*16+(l>>3), chunk (l&7)^(l>>3)
    const unsigned srow0 = (unsigned)(w * 16 + ((lane >> 3) & 7));
    const unsigned kcO = (unsigned)(((lane & 7) ^ (lane >> 3)) << 3);
    const unsigned aO0 = ((unsigned)bm0 + srow0) * 2048u + kcO;
    const unsigned bO0 = ((unsigned)bn0 + srow0) * 2048u + kcO;
    ushort_t* dstA = lds + w * 1024;
    ushort_t* dstB = lds + 16384 + w * 1024;

    float4v acc[2][2][4][2];
#pragma unroll
    for (int i = 0; i < 2; ++i)
#pragma unroll
        for (int j = 0; j < 2; ++j)
#pragma unroll
            for (int m = 0; m < 4; ++m)
#pragma unroll
                for (int n = 0; n < 2; ++n)
                    acc[i][j][m][n] = {0.f, 0.f, 0.f, 0.f};

    short8 X[4], Y[4];           // A banks (one (half,kh) set each)
    short8 U[2], V[2];           // B banks

    // ---- prologue: stage E0's 4 halves; pre-read X<-A0k0, U<-B0k0
    STAGE_A(0, 0, 0);            // S1 (ledger role pP5)
    STAGE_B(0, 0, 0);            // S2 (pP6)
    STAGE_B(0, 1, 0);            // S3 (pP7)
    STAGE_A(0, 1, 0);            // S4 (pP8)
    WVM(4);                      // S1,S2 landed
    BARRIER;
    RD_A4(X, 0, 0, 0);
    RD_B2(U, 0, 0, 0);

    // ---- main loop: iterations 0..NIT-2, last peeled ----
#pragma unroll 1
    for (int it = 0; it < NIT - 1; ++it) {
        const int kO  = 2 * it + 1;
        const int kE2 = 2 * it + 2;
        // ================= tile E (slot 0) =================
        // P1: (A0B0k0)
        WVM(2); WLG; BARRIER;
        STAGE_A(1, 0, kO);
        MM8(0, 0, X, U);
        RD_B2(V, 0, 1, 0);
        // P2: (A0B1k0)
        WVM(2); WLG; BARRIER;
        STAGE_B(1, 0, kO);
        MM8(0, 1, X, V);
        RD_A4(Y, 0, 1, 0);
        // P3: (A1B1k0)
        WLG; BARRIER;
        STAGE_B(1, 1, kO);
        MM8(1, 1, Y, V);
        RD_A4(X, 0, 0, 1);
        // P4: (A1B0k0)
        WLG; BARRIER;
        STAGE_A(1, 1, kO);
        MM8(1, 0, Y, U);
        RD_B2(U, 0, 0, 1);
        // P5: (A0B0k1)
        WLG; BARRIER;
        STAGE_A(0, 0, kE2);
        MM8(0, 0, X, U);
        RD_B2(V, 0, 1, 1);
        // P6: (A0B1k1)
        WLG; BARRIER;
        STAGE_B(0, 0, kE2);
        MM8(0, 1, X, V);
        RD_A4(Y, 0, 1, 1);
        // P7: (A1B1k1)
        WVM(10); WLG; BARRIER;
        STAGE_B(0, 1, kE2);
        MM8(1, 1, Y, V);
        RD_A4(X, 1, 0, 0);
        // P8: (A1B0k1)
        WVM(10); WLG; BARRIER;
        STAGE_A(0, 1, kE2);
        MM8(1, 0, Y, U);
        RD_B2(U, 1, 0, 0);
        // ================= tile O (slot 1) =================
        // P9: (A0B0k0)
        WVM(10); WLG; BARRIER;
        MM8(0, 0, X, U);
        RD_B2(V, 1, 1, 0);
        // P10: (A0B1k0)
        WVM(8); WLG; BARRIER;
        MM8(0, 1, X, V);
        RD_A4(Y, 1, 1, 0);
        // P11: (A1B1k0)
        WLG; BARRIER;
        MM8(1, 1, Y, V);
        RD_A4(X, 1, 0, 1);
        // P12: (A1B0k0)
        WLG; BARRIER;
        MM8(1, 0, Y, U);
        RD_B2(U, 1, 0, 1);
        // P13: (A0B0k1)
        WLG; BARRIER;
        MM8(0, 0, X, U);
        RD_B2(V, 1, 1, 1);
        // P14: (A0B1k1)
        WLG; BARRIER;
        MM8(0, 1, X, V);
        RD_A4(Y, 1, 1, 1);
        // P15: (A1B1k1)
        WVM(6); WLG; BARRIER;
        MM8(1, 1, Y, V);
        RD_A4(X, 0, 0, 0);       // next tile E' (slot 0, restaged at P5)
        // P16: (A1B0k1)
        WVM(4); WLG; BARRIER;
        MM8(1, 0, Y, U);
        RD_B2(U, 0, 0, 0);       // next tile E'
    }

    // ---- peeled last iteration (stages P1-P4 only; no next-tile reads) ----
    {
        const int kO = 2 * (NIT - 1) + 1;
        // P1
        WVM(2); WLG; BARRIER;
        STAGE_A(1, 0, kO);
        MM8(0, 0, X, U);
        RD_B2(V, 0, 1, 0);
        // P2
        WVM(2); WLG; BARRIER;
        STAGE_B(1, 0, kO);
        MM8(0, 1, X, V);
        RD_A4(Y, 0, 1, 0);
        // P3
        WLG; BARRIER;
        STAGE_B(1, 1, kO);
        MM8(1, 1, Y, V);
        RD_A4(X, 0, 0, 1);
        // P4
        WLG; BARRIER;
        STAGE_A(1, 1, kO);
        MM8(1, 0, Y, U);
        RD_B2(U, 0, 0, 1);
        // P5
        WLG; BARRIER;
        MM8(0, 0, X, U);
        RD_B2(V, 0, 1, 1);
        // P6
        WLG; BARRIER;
        MM8(0, 1, X, V);
        RD_A4(Y, 0, 1, 1);
        // P7
        WVM(6); WLG; BARRIER;
        MM8(1, 1, Y, V);
        RD_A4(X, 1, 0, 0);
        // P8
        WVM(4); WLG; BARRIER;
        MM8(1, 0, Y, U);
        RD_B2(U, 1, 0, 0);
        // P9
        WVM(2); WLG; BARRIER;
        MM8(0, 0, X, U);
        RD_B2(V, 1, 1, 0);
        // P10
        WVM(0); WLG; BARRIER;
        MM8(0, 1, X, V);
        RD_A4(Y, 1, 1, 0);
        // P11
        WLG; BARRIER;
        MM8(1, 1, Y, V);
        RD_A4(X, 1, 0, 1);
        // P12
        WLG; BARRIER;
        MM8(1, 0, Y, U);
        RD_B2(U, 1, 0, 1);
        // P13
        WLG; BARRIER;
        MM8(0, 0, X, U);
        RD_B2(V, 1, 1, 1);
        // P14
        WLG; BARRIER;
        MM8(0, 1, X, V);
        RD_A4(Y, 1, 1, 1);
        // P15
        WLG; BARRIER;
        MM8(1, 1, Y, V);
        // P16
        WLG; BARRIER;
        MM8(1, 0, Y, U);
    }

    // C/D layout: col = lane&15, row = (lane>>4)*4 + reg  [m89/m91]
    {
        const int wm2 = w >> 2, wn2 = w & 3;
#pragma unroll
        for (int ha = 0; ha < 2; ++ha)
#pragma unroll
            for (int hb = 0; hb < 2; ++hb)
#pragma unroll
                for (int mi = 0; mi < 4; ++mi)
#pragma unroll
                    for (int ni = 0; ni < 2; ++ni)
#pragma unroll
                        for (int reg = 0; reg < 4; ++reg) {
                            int row = bm0 + ha * 128 + wm2 * 64 + mi * 16 + q * 4 + reg;
                            int col = bn0 + hb * 128 + wn2 * 32 + ni * 16 + r16;
                            C[(size_t)row * GLD + col] = f2bf(acc[ha][hb][mi][ni][reg]);
                        }
    }
}

// ---- fused row pass: softmax*relu (hat) + rh, wave-per-row, no syncs -------
__global__ __launch_bounds__(256) void row_pass(
    ushort_t* __restrict__ G, const float* __restrict__ bias_c,
    const float* __restrict__ bias_hat, const float* __restrict__ bias_r,
    const float* __restrict__ hidden, ushort_t* __restrict__ rh)
{
    const int wave = threadIdx.x >> 6, lane = threadIdx.x & 63;
    const size_t row = (size_t)blockIdx.x * 4 + wave;
    ushort_t* g = G + row * GLD;
    const int c0 = lane * 16;

    float cv[16];
    {
        short8 a = *(const short8*)(g + c0);
        short8 b = *(const short8*)(g + c0 + 8);
#pragma unroll
        for (int i = 0; i < 8; ++i) {
            cv[i]     = bf2f((ushort_t)a[i]) + bias_c[c0 + i];
            cv[8 + i] = bf2f((ushort_t)b[i]) + bias_c[c0 + 8 + i];
        }
    }
    float mx = cv[0];
#pragma unroll
    for (int i = 1; i < 16; ++i) mx = fmaxf(mx, cv[i]);
#pragma unroll
    for (int m = 1; m < 64; m <<= 1) mx = fmaxf(mx, __shfl_xor(mx, m));
    float sum = 0.f;
#pragma unroll
    for (int i = 0; i < 16; ++i) { cv[i] = __expf(cv[i] - mx); sum += cv[i]; }
#pragma unroll
    for (int m = 1; m < 64; m <<= 1) sum += __shfl_xor(sum, m);
    const float inv = 1.0f / sum;

    {
        short8 a = *(const short8*)(g + 1024 + c0);
        short8 b = *(const short8*)(g + 1024 + c0 + 8);
        short8 oa, ob;
#pragma unroll
        for (int i = 0; i < 8; ++i) {
            float ha = bf2f((ushort_t)a[i]) + bias_hat[c0 + i];
            float hb = bf2f((ushort_t)b[i]) + bias_hat[c0 + 8 + i];
            oa[i] = (short)f2bf(cv[i] * inv * fmaxf(ha, 0.f));
            ob[i] = (short)f2bf(cv[8 + i] * inv * fmaxf(hb, 0.f));
        }
        *(short8*)(g + c0) = oa;
        *(short8*)(g + c0 + 8) = ob;
    }

    {
        short8 a = *(const short8*)(g + 2048 + c0);
        short8 b = *(const short8*)(g + 2048 + c0 + 8);
        const float* hp = hidden + row * 1024 + c0;
        short8 oa, ob;
#pragma unroll
        for (int i = 0; i < 8; ++i) {
            float ra = 1.0f / (1.0f + __expf(-(bf2f((ushort_t)a[i]) + bias_r[c0 + i])));
            float rb = 1.0f / (1.0f + __expf(-(bf2f((ushort_t)b[i]) + bias_r[c0 + 8 + i])));
            oa[i] = (short)f2bf(ra * hp[i]);
            ob[i] = (short)f2bf(rb * hp[8 + i]);
        }
        ushort_t* rp = rh + row * 1024 + c0;
        *(short8*)rp = oa;
        *(short8*)(rp + 8) = ob;
    }
}

// ---- GEMM2 + fused final epilogue, 64x128 tile for TLP ---------------------
// t6 = rh @ Whh^T; out = (1-z)*tanh(xh + bias_h + t6) + z*hidden + hat
#define CSTRIDE 132
__global__ __launch_bounds__(256) void gemm2_final(
    const ushort_t* __restrict__ A, const ushort_t* __restrict__ B,
    const ushort_t* __restrict__ G, const float* __restrict__ bias_z,
    const float* __restrict__ bias_h, const float* __restrict__ hidden,
    float* __restrict__ out)
{
    const int bn0 = blockIdx.x * 128;
    const int bm0 = blockIdx.y * 64;

    __shared__ ushort_t smem[64 * CSTRIDE];   // 16.5 KiB; K-loop uses first 12 KiB
    ushort_t* As = smem;            // 64 x 32
    ushort_t* Bs = smem + 2048;     // 128 x 32

    const int t = threadIdx.x;
    const int wave = t >> 6, lane = t & 63;
    const int wr = wave >> 1, wcq = wave & 1;    // 2x2 wave grid: 32m x 64n each
    const int q = lane >> 4, r16 = lane & 15;
    const int lrow = lane >> 2;
    const int lcol = (lane & 3) * 8;

    float4v acc[2][4];
#pragma unroll
    for (int i = 0; i < 2; ++i)
#pragma unroll
        for (int j = 0; j < 4; ++j)
            acc[i][j] = {0.f, 0.f, 0.f, 0.f};

    for (int k0 = 0; k0 < 1024; k0 += 32) {
        // 12 chunks of 16 rows (A: 0..3, B: 4..11), 3 per wave
#pragma unroll
        for (int j = 0; j < 3; ++j) {
            int l = wave * 3 + j;
            if (l < 4) {
                const ushort_t* gp = A + (size_t)(bm0 + l * 16 + lrow) * 1024 + k0 + lcol;
                __builtin_amdgcn_global_load_lds(
                    (const __attribute__((address_space(1))) void*)gp,
                    (__attribute__((address_space(3))) void*)(As + l * 512),
                    16, 0, 0);
            } else {
                const ushort_t* gp = B + (size_t)(bn0 + (l - 4) * 16 + lrow) * 1024 + k0 + lcol;
                __builtin_amdgcn_global_load_lds(
                    (const __attribute__((address_space(1))) void*)gp,
                    (__attribute__((address_space(3))) void*)(Bs + (l - 4) * 512),
                    16, 0, 0);
            }
        }
        __syncthreads();

        short8 af[2], bf[4];
#pragma unroll
        for (int mi = 0; mi < 2; ++mi)
            af[mi] = *(const short8*)&As[(wr * 32 + mi * 16 + r16) * 32 + q * 8];
#pragma unroll
        for (int ni = 0; ni < 4; ++ni)
            bf[ni] = *(const short8*)&Bs[(wcq * 64 + ni * 16 + r16) * 32 + q * 8];
#pragma unroll
        for (int mi = 0; mi < 2; ++mi)
#pragma unroll
            for (int ni = 0; ni < 4; ++ni)
                acc[mi][ni] = __builtin_amdgcn_mfma_f32_16x16x32_bf16(
                    af[mi], bf[ni], acc[mi][ni], 0, 0, 0);
        __syncthreads();
    }

    // stage t6 tile to LDS (bf16), then coalesced epilogue
#pragma unroll
    for (int mi = 0; mi < 2; ++mi)
#pragma unroll
        for (int ni = 0; ni < 4; ++ni)
#pragma unroll
            for (int reg = 0; reg < 4; ++reg) {
                int rl = wr * 32 + mi * 16 + q * 4 + reg;
                int cl = wcq * 64 + ni * 16 + r16;
                smem[rl * CSTRIDE + cl] = f2bf(acc[mi][ni][reg]);
            }
    __syncthreads();

    const int colL = t & 127;
    const int gc = bn0 + colL;
    const float bz = bias_z[gc];
    const float bh = bias_h[gc];
    const int rbase = t >> 7;                  // 0 or 1
#pragma unroll 4
    for (int pass = 0; pass < 32; ++pass) {
        const int rowL = pass * 2 + rbase;
        const size_t gr = (size_t)(bm0 + rowL);
        const ushort_t* grow = G + gr * GLD;
        float z = 1.0f / (1.0f + __expf(-(bf2f(grow[3072 + gc]) + bz)));
        float targ = bf2f(grow[4096 + gc]) + bh + bf2f(smem[rowL * CSTRIDE + colL]);
        float th = 1.0f - 2.0f / (__expf(2.0f * targ) + 1.0f);
        out[gr * 1024 + gc] =
            (1.0f - z) * th + z * hidden[gr * 1024 + gc] + bf2f(grow[gc]);
    }
}

// ---- launch ----------------------------------------------------------------

extern "C" void kernel_launch(void* const* d_in, const int* in_sizes, int n_in,
                              void* d_out, int out_size, void* d_ws, size_t ws_size,
                              hipStream_t stream)
{
    const float* x        = (const float*)d_in[0];
    const float* hidden   = (const float*)d_in[1];
    const float* wxr      = (const float*)d_in[2];
    const float* whr      = (const float*)d_in[3];
    const float* bias_r   = (const float*)d_in[4];
    const float* wxz      = (const float*)d_in[5];
    const float* whz      = (const float*)d_in[6];
    const float* bias_z   = (const float*)d_in[7];
    const float* wxh      = (const float*)d_in[8];
    const float* whh      = (const float*)d_in[9];
    const float* bias_h   = (const float*)d_in[10];
    const float* wc       = (const float*)d_in[11];
    const float* bias_c   = (const float*)d_in[12];
    const float* what     = (const float*)d_in[13];
    const float* bias_hat = (const float*)d_in[14];
    float* out = (float*)d_out;

    char* ws = (char*)d_ws;
    ushort_t* G     = (ushort_t*)(ws);                    // [8192,5120] bf16, 80 MiB
    ushort_t* Abf   = (ushort_t*)(ws + 83886080);         // [8192,2048] bf16, 32 MiB
    ushort_t* Wbf   = (ushort_t*)(ws + 117440512);        // [5120,2048] bf16, 20 MiB
    ushort_t* Whhbf = (ushort_t*)(ws + 138412032);        // [1024,1024] bf16,  2 MiB
    ushort_t* rhbf  = (ushort_t*)(ws + 140509184);        // [8192,1024] bf16, 16 MiB

    pack_all<<<27648, 256, 0, stream>>>(x, hidden, wc, what, wxr, whr, wxz, whz,
                                        wxh, whh, Abf, Wbf, Whhbf);

    // GEMM1: G = Abf @ Wbf^T   (M=8192, N=5120, K=2048; xh region K=1024)
    gemm1<<<640, 512, 0, stream>>>(Abf, Wbf, G);

    // fused softmax/hat + rh (wave per row)
    row_pass<<<B_ROWS / 4, 256, 0, stream>>>(G, bias_c, bias_hat, bias_r, hidden, rhbf);

    // GEMM2 + final epilogue -> out
    gemm2_final<<<dim3(8, 128), 256, 0, stream>>>(rhbf, Whhbf, G, bias_z, bias_h,
                                                  hidden, out);
}

// Round 8
// 354.498 us; speedup vs baseline: 1.1462x; 1.0242x over previous
//
#include <hip/hip_runtime.h>

typedef unsigned short ushort_t;
typedef __attribute__((ext_vector_type(8))) short short8;
typedef __attribute__((ext_vector_type(4))) float float4v;
typedef __attribute__((ext_vector_type(4))) ushort_t ushort4v;

#define B_ROWS 8192
#define HDIM   1024
#define GLD    5120   // G cols: [hat(c) | hat_raw | r | z | xh]

__device__ __forceinline__ float bf2f(ushort_t u) {
    return __uint_as_float(((unsigned)u) << 16);
}
__device__ __forceinline__ ushort_t f2bf(float f) {
    unsigned u = __float_as_uint(f);
    u += 0x7FFFu + ((u >> 16) & 1u);   // round-to-nearest-even
    return (ushort_t)(u >> 16);
}

// ---- one pack kernel for A, W, Whh ----------------------------------------
__global__ __launch_bounds__(256) void pack_all(
    const float* __restrict__ x, const float* __restrict__ h,
    const float* __restrict__ wc, const float* __restrict__ what,
    const float* __restrict__ wxr, const float* __restrict__ whr,
    const float* __restrict__ wxz, const float* __restrict__ whz,
    const float* __restrict__ wxh, const float* __restrict__ whh,
    ushort_t* __restrict__ A, ushort_t* __restrict__ W,
    ushort_t* __restrict__ Whh)
{
    const int bid = blockIdx.x;
    float4v v;
    ushort_t* dst;
    size_t i4;
    if (bid < 16384) {                       // ---- A = [x | hidden]
        i4 = ((size_t)bid * 256 + threadIdx.x) * 4;
        int c = (int)(i4 & 2047);
        size_t b = i4 >> 11;
        const float* src = (c < 1024) ? (x + b * 1024 + c)
                                      : (h + b * 1024 + (c - 1024));
        v = *(const float4v*)src;
        dst = A + i4;
    } else if (bid < 26624) {                // ---- W rows: wc|what|[xr|hr]|[xz|hz]|[xh|junk]
        i4 = ((size_t)(bid - 16384) * 256 + threadIdx.x) * 4;
        int j = (int)(i4 >> 11);
        int k = (int)(i4 & 2047);
        int r = j >> 10, jr = j & 1023;
        if (r == 0) {
            v = *(const float4v*)(wc + (size_t)j * 2048 + k);
        } else if (r == 1) {
            v = *(const float4v*)(what + (size_t)jr * 2048 + k);
        } else if (r == 4) {
            v = (k < 1024) ? *(const float4v*)(wxh + (size_t)jr * 1024 + k)
                           : (float4v){0.f, 0.f, 0.f, 0.f};
        } else {
            const float* p0 = (r == 2) ? wxr : wxz;
            const float* p1 = (r == 2) ? whr : whz;
            const float* p = (k < 1024) ? (p0 + (size_t)jr * 1024 + k)
                                        : (p1 + (size_t)jr * 1024 + (k - 1024));
            v = *(const float4v*)p;
        }
        dst = W + i4;
    } else {                                 // ---- Whh
        i4 = ((size_t)(bid - 26624) * 256 + threadIdx.x) * 4;
        v = *(const float4v*)(whh + i4);
        dst = Whh + i4;
    }
    ushort4v o;
#pragma unroll
    for (int t = 0; t < 4; ++t) o[t] = f2bf(v[t]);
    *(ushort4v*)dst = o;
}

// ---- GEMM1: G = A @ W^T -----------------------------------------------------
// R8: reads-BEFORE-MFMA 16-phase schedule. R7's counters proved spill fixed
// (WRITE=81920) but phase wall = 687cyc = MFMA(310) + DS(290) serial: reads
// sat AFTER the MFMA cluster, so the barrier-locked waves ran the two pipes
// back-to-back. Fix: quadrant order (A0B0)(A1B0)(A0B1)(A1B1) per kh makes
// every refill target a bank NOT used by the current phase's MFMA, so reads
// move BEFORE the cluster and the DS pipe overlaps the MFMA window.
// Phase = {vmcnt(N); lgkm(0); barrier; stage; reads(P+1 frags); MFMA(P)}.
// Banks X(A0),Y(A1),U(B0),V(B1) = 48 frag VGPRs (R7-verified no-spill).
// Per-tile reads p1..p8: Y,V,U,X,Y,V,U,X (4/2/2/4 balanced); every read's
// old content last used >=1 phase earlier; first use >=1 phase later.
// Stages P1-P8: B(s1,0) A(s1,0) A(s1,1) B(s1,1) B(s0,0)' A(s0,0)' A(s0,1)'
// B(s0,1)'; every stage >=2 phases after the buffer's last LDS read; every
// stage >=6 phases before its first read (>>900cyc HBM latency).
// vmcnt ledger (2 loads/stage, in-order): P1:2 P2:2 P7:10 P8:10 P9:10
// P10:8 P15:6 P16:4; peel: P7:6 P8:4 P9:2 P10:0.
// LDS: 8 half-buffers [128 rows][64 k], zero-conflict XOR pattern
// (R2-verified): LDS chunk c of row r = global chunk c^(r&7).

#define GLOAD(gp, lp) __builtin_amdgcn_global_load_lds( \
    (const __attribute__((address_space(1))) void*)(gp), \
    (__attribute__((address_space(3))) void*)(lp), 16, 0, 0)

#define BARRIER do { __builtin_amdgcn_s_barrier(); \
    __builtin_amdgcn_sched_barrier(0); } while (0)
#define WLG do { \
    asm volatile("s_waitcnt lgkmcnt(0)" ::: "memory"); \
    __builtin_amdgcn_sched_barrier(0); } while (0)
#define WVM(N) do { \
    asm volatile("s_waitcnt vmcnt(" #N ")" ::: "memory"); \
    __builtin_amdgcn_sched_barrier(0); } while (0)

// stage one 128x64 half-tile: 8 waves x 2 GLOADs x 1KB = 16KB
#define STAGE_A(S, H, KT) do { \
    GLOAD(A + (aO0 + (H) * 262144u + (unsigned)(KT) * 64u), \
          dstA + (S) * 32768 + (H) * 8192); \
    GLOAD(A + (aO0 + 16384u + (H) * 262144u + (unsigned)(KT) * 64u), \
          dstA + (S) * 32768 + (H) * 8192 + 512); } while (0)
#define STAGE_B(S, H, KT) do { \
    GLOAD(B + (bO0 + (H) * 262144u + (unsigned)(KT) * 64u), \
          dstB + (S) * 32768 + (H) * 8192); \
    GLOAD(B + (bO0 + 16384u + (H) * 262144u + (unsigned)(KT) * 64u), \
          dstB + (S) * 32768 + (H) * 8192 + 512); } while (0)

// 4 ds_read_b128: one (A-half, kh) set into bank BK
#define RD_A4(BK, S, H, KH) do { \
    _Pragma("unroll") \
    for (int mi = 0; mi < 4; ++mi) \
        BK[mi] = *(const short8*)(lds + (S) * 32768 + (H) * 8192 + mi * 1024 \
                                  + ((KH) ? Ard1 : Ard0)); } while (0)

// 2 ds_read_b128: one (B-half, kh) set into bank BK
#define RD_B2(BK, S, H, KH) do { \
    _Pragma("unroll") \
    for (int ni = 0; ni < 2; ++ni) \
        BK[ni] = *(const short8*)(lds + 16384 + (S) * 32768 + (H) * 8192 + ni * 1024 \
                                  + ((KH) ? Brd1 : Brd0)); } while (0)

// 8 MFMA: one (quadrant, kh) cell
#define MM8(HA, HB, AB, BB) do { \
    __builtin_amdgcn_s_setprio(1); \
    _Pragma("unroll") \
    for (int mi = 0; mi < 4; ++mi) { \
        _Pragma("unroll") \
        for (int ni = 0; ni < 2; ++ni) \
            acc[HA][HB][mi][ni] = __builtin_amdgcn_mfma_f32_16x16x32_bf16( \
                AB[mi], BB[ni], acc[HA][HB][mi][ni], 0, 0, 0); } \
    __builtin_amdgcn_s_setprio(0); } while (0)

__global__ __launch_bounds__(512, 2) void gemm1(
    const ushort_t* __restrict__ A, const ushort_t* __restrict__ B,
    ushort_t* __restrict__ C)
{
    // heavy blocks (K=2048) first, light (K=1024) last; XCD-striped within each
    const int bid = blockIdx.x;
    int bx, by;
    if (bid < 512) { int hI = (bid & 7) * 64 + (bid >> 3); by = hI >> 4; bx = hI & 15; }
    else           { int b = bid - 512; int lI = (b & 7) * 16 + (b >> 3); by = lI >> 2; bx = 16 + (lI & 3); }
    const int bn0 = bx * 256;
    const int bm0 = by * 256;
    const int K = (bx >= 16) ? 1024 : 2048;
    const int NIT = K >> 7;                      // 2 K-tiles (128 k) per iter

    __shared__ ushort_t lds[65536];              // 128 KiB
    // element offsets: A(s,h) = s*32768 + h*8192 ; B(s,h) = 16384 + s*32768 + h*8192

    const int t = threadIdx.x;
    const int w = t >> 6, lane = t & 63;
    const int q = lane >> 4, r16 = lane & 15;

    // ---- ds_read bases (4 live VGPRs; S/H/mi fold into ds offset imm)
    const int c0 = ((q ^ (r16 & 7)) << 3);           // kh0 chunk
    const int c1 = (((4 + q) ^ (r16 & 7)) << 3);     // kh1 chunk
    const int Ard0 = ((w >> 2) * 64 + r16) * 64 + c0;
    const int Ard1 = ((w >> 2) * 64 + r16) * 64 + c1;
    const int Brd0 = ((w & 3) * 32 + r16) * 64 + c0;
    const int Brd1 = ((w & 3) * 32 + r16) * 64 + c1;

    // ---- staging: lane l of wave w writes row w*16+(l>>3), chunk (l&7)^(l>>3)
    const unsigned srow0 = (unsigned)(w * 16 + ((lane >> 3) & 7));
    const unsigned kcO = (unsigned)(((lane & 7) ^ (lane >> 3)) << 3);
    const unsigned aO0 = ((unsigned)bm0 + srow0) * 2048u + kcO;
    const unsigned bO0 = ((unsigned)bn0 + srow0) * 2048u + kcO;
    ushort_t* dstA = lds + w * 1024;
    ushort_t* dstB = lds + 16384 + w * 1024;

    float4v acc[2][2][4][2];
#pragma unroll
    for (int i = 0; i < 2; ++i)
#pragma unroll
        for (int j = 0; j < 2; ++j)
#pragma unroll
            for (int m = 0; m < 4; ++m)
#pragma unroll
                for (int n = 0; n < 2; ++n)
                    acc[i][j][m][n] = {0.f, 0.f, 0.f, 0.f};

    short8 X[4], Y[4];           // A banks: X=A-half0, Y=A-half1 (one kh set)
    short8 U[2], V[2];           // B banks: U=B-half0, V=B-half1

    // ---- prologue: stage E0 in S5..S8 role order; pre-read X<-A00k0, U<-B00k0
    STAGE_B(0, 0, 0);            // S5-role
    STAGE_A(0, 0, 0);            // S6-role
    STAGE_A(0, 1, 0);            // S7-role
    STAGE_B(0, 1, 0);            // S8-role
    WVM(4);                      // B(0,0), A(0,0) landed
    BARRIER;
    RD_A4(X, 0, 0, 0);
    RD_B2(U, 0, 0, 0);

    // ---- main loop: iterations 0..NIT-2, last peeled ----
#pragma unroll 1
    for (int it = 0; it < NIT - 1; ++it) {
        const int kO  = 2 * it + 1;
        const int kE2 = 2 * it + 2;
        // ===== tile E (slot 0): quadrants (A0B0)(A1B0)(A0B1)(A1B1) x kh =====
        // P1: MFMA(X,U)k0 | stage B(s1,0)@O | read Y<-A(0,1)k0
        WVM(2); WLG; BARRIER;
        STAGE_B(1, 0, kO);
        RD_A4(Y, 0, 1, 0);
        MM8(0, 0, X, U);
        // P2: MFMA(Y,U)k0 | stage A(s1,0)@O | read V<-B(0,1)k0
        WVM(2); WLG; BARRIER;
        STAGE_A(1, 0, kO);
        RD_B2(V, 0, 1, 0);
        MM8(1, 0, Y, U);
        // P3: MFMA(X,V)k0 | stage A(s1,1)@O | read U<-B(0,0)k1
        WLG; BARRIER;
        STAGE_A(1, 1, kO);
        RD_B2(U, 0, 0, 1);
        MM8(0, 1, X, V);
        // P4: MFMA(Y,V)k0 | stage B(s1,1)@O | read X<-A(0,0)k1
        WLG; BARRIER;
        STAGE_B(1, 1, kO);
        RD_A4(X, 0, 0, 1);
        MM8(1, 1, Y, V);
        // P5: MFMA(X,U)k1 | stage B(s0,0)@E' | read Y<-A(0,1)k1
        WLG; BARRIER;
        STAGE_B(0, 0, kE2);
        RD_A4(Y, 0, 1, 1);
        MM8(0, 0, X, U);
        // P6: MFMA(Y,U)k1 | stage A(s0,0)@E' | read V<-B(0,1)k1
        WLG; BARRIER;
        STAGE_A(0, 0, kE2);
        RD_B2(V, 0, 1, 1);
        MM8(1, 0, Y, U);
        // P7: MFMA(X,V)k1 | stage A(s0,1)@E' | read U<-B(1,0)k0
        WVM(10); WLG; BARRIER;
        STAGE_A(0, 1, kE2);
        RD_B2(U, 1, 0, 0);
        MM8(0, 1, X, V);
        // P8: MFMA(Y,V)k1 | stage B(s0,1)@E' | read X<-A(1,0)k0
        WVM(10); WLG; BARRIER;
        STAGE_B(0, 1, kE2);
        RD_A4(X, 1, 0, 0);
        MM8(1, 1, Y, V);
        // ===== tile O (slot 1) =====
        // P9: read Y<-A(1,1)k0
        WVM(10); WLG; BARRIER;
        RD_A4(Y, 1, 1, 0);
        MM8(0, 0, X, U);
        // P10: read V<-B(1,1)k0
        WVM(8); WLG; BARRIER;
        RD_B2(V, 1, 1, 0);
        MM8(1, 0, Y, U);
        // P11: read U<-B(1,0)k1
        WLG; BARRIER;
        RD_B2(U, 1, 0, 1);
        MM8(0, 1, X, V);
        // P12: read X<-A(1,0)k1
        WLG; BARRIER;
        RD_A4(X, 1, 0, 1);
        MM8(1, 1, Y, V);
        // P13: read Y<-A(1,1)k1
        WLG; BARRIER;
        RD_A4(Y, 1, 1, 1);
        MM8(0, 0, X, U);
        // P14: read V<-B(1,1)k1
        WLG; BARRIER;
        RD_B2(V, 1, 1, 1);
        MM8(1, 0, Y, U);
        // P15: read U<-B(0,0)'k0 (next E, staged P5)
        WVM(6); WLG; BARRIER;
        RD_B2(U, 0, 0, 0);
        MM8(0, 1, X, V);
        // P16: read X<-A(0,0)'k0 (next E, staged P6)
        WVM(4); WLG; BARRIER;
        RD_A4(X, 0, 0, 0);
        MM8(1, 1, Y, V);
    }

    // ---- peeled last iteration (stages P1-P4 only; no next-tile reads) ----
    {
        const int kO = 2 * (NIT - 1) + 1;
        // P1
        WVM(2); WLG; BARRIER;
        STAGE_B(1, 0, kO);
        RD_A4(Y, 0, 1, 0);
        MM8(0, 0, X, U);
        // P2
        WVM(2); WLG; BARRIER;
        STAGE_A(1, 0, kO);
        RD_B2(V, 0, 1, 0);
        MM8(1, 0, Y, U);
        // P3
        WLG; BARRIER;
        STAGE_A(1, 1, kO);
        RD_B2(U, 0, 0, 1);
        MM8(0, 1, X, V);
        // P4
        WLG; BARRIER;
        STAGE_B(1, 1, kO);
        RD_A4(X, 0, 0, 1);
        MM8(1, 1, Y, V);
        // P5
        WLG; BARRIER;
        RD_A4(Y, 0, 1, 1);
        MM8(0, 0, X, U);
        // P6
        WLG; BARRIER;
        RD_B2(V, 0, 1, 1);
        MM8(1, 0, Y, U);
        // P7
        WVM(6); WLG; BARRIER;
        RD_B2(U, 1, 0, 0);
        MM8(0, 1, X, V);
        // P8
        WVM(4); WLG; BARRIER;
        RD_A4(X, 1, 0, 0);
        MM8(1, 1, Y, V);
        // P9
        WVM(2); WLG; BARRIER;
        RD_A4(Y, 1, 1, 0);
        MM8(0, 0, X, U);
        // P10
        WVM(0); WLG; BARRIER;
        RD_B2(V, 1, 1, 0);
        MM8(1, 0, Y, U);
        // P11
        WLG; BARRIER;
        RD_B2(U, 1, 0, 1);
        MM8(0, 1, X, V);
        // P12
        WLG; BARRIER;
        RD_A4(X, 1, 0, 1);
        MM8(1, 1, Y, V);
        // P13
        WLG; BARRIER;
        RD_A4(Y, 1, 1, 1);
        MM8(0, 0, X, U);
        // P14
        WLG; BARRIER;
        RD_B2(V, 1, 1, 1);
        MM8(1, 0, Y, U);
        // P15
        WLG; BARRIER;
        MM8(0, 1, X, V);
        // P16
        WLG; BARRIER;
        MM8(1, 1, Y, V);
    }

    // C/D layout: col = lane&15, row = (lane>>4)*4 + reg  [m89/m91]
    {
        const int wm2 = w >> 2, wn2 = w & 3;
#pragma unroll
        for (int ha = 0; ha < 2; ++ha)
#pragma unroll
            for (int hb = 0; hb < 2; ++hb)
#pragma unroll
                for (int mi = 0; mi < 4; ++mi)
#pragma unroll
                    for (int ni = 0; ni < 2; ++ni)
#pragma unroll
                        for (int reg = 0; reg < 4; ++reg) {
                            int row = bm0 + ha * 128 + wm2 * 64 + mi * 16 + q * 4 + reg;
                            int col = bn0 + hb * 128 + wn2 * 32 + ni * 16 + r16;
                            C[(size_t)row * GLD + col] = f2bf(acc[ha][hb][mi][ni][reg]);
                        }
    }
}

// ---- fused row pass: softmax*relu (hat) + rh, wave-per-row, no syncs -------
__global__ __launch_bounds__(256) void row_pass(
    ushort_t* __restrict__ G, const float* __restrict__ bias_c,
    const float* __restrict__ bias_hat, const float* __restrict__ bias_r,
    const float* __restrict__ hidden, ushort_t* __restrict__ rh)
{
    const int wave = threadIdx.x >> 6, lane = threadIdx.x & 63;
    const size_t row = (size_t)blockIdx.x * 4 + wave;
    ushort_t* g = G + row * GLD;
    const int c0 = lane * 16;

    float cv[16];
    {
        short8 a = *(const short8*)(g + c0);
        short8 b = *(const short8*)(g + c0 + 8);
#pragma unroll
        for (int i = 0; i < 8; ++i) {
            cv[i]     = bf2f((ushort_t)a[i]) + bias_c[c0 + i];
            cv[8 + i] = bf2f((ushort_t)b[i]) + bias_c[c0 + 8 + i];
        }
    }
    float mx = cv[0];
#pragma unroll
    for (int i = 1; i < 16; ++i) mx = fmaxf(mx, cv[i]);
#pragma unroll
    for (int m = 1; m < 64; m <<= 1) mx = fmaxf(mx, __shfl_xor(mx, m));
    float sum = 0.f;
#pragma unroll
    for (int i = 0; i < 16; ++i) { cv[i] = __expf(cv[i] - mx); sum += cv[i]; }
#pragma unroll
    for (int m = 1; m < 64; m <<= 1) sum += __shfl_xor(sum, m);
    const float inv = 1.0f / sum;

    {
        short8 a = *(const short8*)(g + 1024 + c0);
        short8 b = *(const short8*)(g + 1024 + c0 + 8);
        short8 oa, ob;
#pragma unroll
        for (int i = 0; i < 8; ++i) {
            float ha = bf2f((ushort_t)a[i]) + bias_hat[c0 + i];
            float hb = bf2f((ushort_t)b[i]) + bias_hat[c0 + 8 + i];
            oa[i] = (short)f2bf(cv[i] * inv * fmaxf(ha, 0.f));
            ob[i] = (short)f2bf(cv[8 + i] * inv * fmaxf(hb, 0.f));
        }
        *(short8*)(g + c0) = oa;
        *(short8*)(g + c0 + 8) = ob;
    }

    {
        short8 a = *(const short8*)(g + 2048 + c0);
        short8 b = *(const short8*)(g + 2048 + c0 + 8);
        const float* hp = hidden + row * 1024 + c0;
        short8 oa, ob;
#pragma unroll
        for (int i = 0; i < 8; ++i) {
            float ra = 1.0f / (1.0f + __expf(-(bf2f((ushort_t)a[i]) + bias_r[c0 + i])));
            float rb = 1.0f / (1.0f + __expf(-(bf2f((ushort_t)b[i]) + bias_r[c0 + 8 + i])));
            oa[i] = (short)f2bf(ra * hp[i]);
            ob[i] = (short)f2bf(rb * hp[8 + i]);
        }
        ushort_t* rp = rh + row * 1024 + c0;
        *(short8*)rp = oa;
        *(short8*)(rp + 8) = ob;
    }
}

// ---- GEMM2 + fused final epilogue, 64x128 tile for TLP ---------------------
// t6 = rh @ Whh^T; out = (1-z)*tanh(xh + bias_h + t6) + z*hidden + hat
#define CSTRIDE 132
__global__ __launch_bounds__(256) void gemm2_final(
    const ushort_t* __restrict__ A, const ushort_t* __restrict__ B,
    const ushort_t* __restrict__ G, const float* __restrict__ bias_z,
    const float* __restrict__ bias_h, const float* __restrict__ hidden,
    float* __restrict__ out)
{
    const int bn0 = blockIdx.x * 128;
    const int bm0 = blockIdx.y * 64;

    __shared__ ushort_t smem[64 * CSTRIDE];   // 16.5 KiB; K-loop uses first 12 KiB
    ushort_t* As = smem;            // 64 x 32
    ushort_t* Bs = smem + 2048;     // 128 x 32

    const int t = threadIdx.x;
    const int wave = t >> 6, lane = t & 63;
    const int wr = wave >> 1, wcq = wave & 1;    // 2x2 wave grid: 32m x 64n each
    const int q = lane >> 4, r16 = lane & 15;
    const int lrow = lane >> 2;
    const int lcol = (lane & 3) * 8;

    float4v acc[2][4];
#pragma unroll
    for (int i = 0; i < 2; ++i)
#pragma unroll
        for (int j = 0; j < 4; ++j)
            acc[i][j] = {0.f, 0.f, 0.f, 0.f};

    for (int k0 = 0; k0 < 1024; k0 += 32) {
        // 12 chunks of 16 rows (A: 0..3, B: 4..11), 3 per wave
#pragma unroll
        for (int j = 0; j < 3; ++j) {
            int l = wave * 3 + j;
            if (l < 4) {
                const ushort_t* gp = A + (size_t)(bm0 + l * 16 + lrow) * 1024 + k0 + lcol;
                __builtin_amdgcn_global_load_lds(
                    (const __attribute__((address_space(1))) void*)gp,
                    (__attribute__((address_space(3))) void*)(As + l * 512),
                    16, 0, 0);
            } else {
                const ushort_t* gp = B + (size_t)(bn0 + (l - 4) * 16 + lrow) * 1024 + k0 + lcol;
                __builtin_amdgcn_global_load_lds(
                    (const __attribute__((address_space(1))) void*)gp,
                    (__attribute__((address_space(3))) void*)(Bs + (l - 4) * 512),
                    16, 0, 0);
            }
        }
        __syncthreads();

        short8 af[2], bf[4];
#pragma unroll
        for (int mi = 0; mi < 2; ++mi)
            af[mi] = *(const short8*)&As[(wr * 32 + mi * 16 + r16) * 32 + q * 8];
#pragma unroll
        for (int ni = 0; ni < 4; ++ni)
            bf[ni] = *(const short8*)&Bs[(wcq * 64 + ni * 16 + r16) * 32 + q * 8];
#pragma unroll
        for (int mi = 0; mi < 2; ++mi)
#pragma unroll
            for (int ni = 0; ni < 4; ++ni)
                acc[mi][ni] = __builtin_amdgcn_mfma_f32_16x16x32_bf16(
                    af[mi], bf[ni], acc[mi][ni], 0, 0, 0);
        __syncthreads();
    }

    // stage t6 tile to LDS (bf16), then coalesced epilogue
#pragma unroll
    for (int mi = 0; mi < 2; ++mi)
#pragma unroll
        for (int ni = 0; ni < 4; ++ni)
#pragma unroll
            for (int reg = 0; reg < 4; ++reg) {
                int rl = wr * 32 + mi * 16 + q * 4 + reg;
                int cl = wcq * 64 + ni * 16 + r16;
                smem[rl * CSTRIDE + cl] = f2bf(acc[mi][ni][reg]);
            }
    __syncthreads();

    const int colL = t & 127;
    const int gc = bn0 + colL;
    const float bz = bias_z[gc];
    const float bh = bias_h[gc];
    const int rbase = t >> 7;                  // 0 or 1
#pragma unroll 4
    for (int pass = 0; pass < 32; ++pass) {
        const int rowL = pass * 2 + rbase;
        const size_t gr = (size_t)(bm0 + rowL);
        const ushort_t* grow = G + gr * GLD;
        float z = 1.0f / (1.0f + __expf(-(bf2f(grow[3072 + gc]) + bz)));
        float targ = bf2f(grow[4096 + gc]) + bh + bf2f(smem[rowL * CSTRIDE + colL]);
        float th = 1.0f - 2.0f / (__expf(2.0f * targ) + 1.0f);
        out[gr * 1024 + gc] =
            (1.0f - z) * th + z * hidden[gr * 1024 + gc] + bf2f(grow[gc]);
    }
}

// ---- launch ----------------------------------------------------------------

extern "C" void kernel_launch(void* const* d_in, const int* in_sizes, int n_in,
                              void* d_out, int out_size, void* d_ws, size_t ws_size,
                              hipStream_t stream)
{
    const float* x        = (const float*)d_in[0];
    const float* hidden   = (const float*)d_in[1];
    const float* wxr      = (const float*)d_in[2];
    const float* whr      = (const float*)d_in[3];
    const float* bias_r   = (const float*)d_in[4];
    const float* wxz      = (const float*)d_in[5];
    const float* whz      = (const float*)d_in[6];
    const float* bias_z   = (const float*)d_in[7];
    const float* wxh      = (const float*)d_in[8];
    const float* whh      = (const float*)d_in[9];
    const float* bias_h   = (const float*)d_in[10];
    const float* wc       = (const float*)d_in[11];
    const float* bias_c   = (const float*)d_in[12];
    const float* what     = (const float*)d_in[13];
    const float* bias_hat = (const float*)d_in[14];
    float* out = (float*)d_out;

    char* ws = (char*)d_ws;
    ushort_t* G     = (ushort_t*)(ws);                    // [8192,5120] bf16, 80 MiB
    ushort_t* Abf   = (ushort_t*)(ws + 83886080);         // [8192,2048] bf16, 32 MiB
    ushort_t* Wbf   = (ushort_t*)(ws + 117440512);        // [5120,2048] bf16, 20 MiB
    ushort_t* Whhbf = (ushort_t*)(ws + 138412032);        // [1024,1024] bf16,  2 MiB
    ushort_t* rhbf  = (ushort_t*)(ws + 140509184);        // [8192,1024] bf16, 16 MiB

    pack_all<<<27648, 256, 0, stream>>>(x, hidden, wc, what, wxr, whr, wxz, whz,
                                        wxh, whh, Abf, Wbf, Whhbf);

    // GEMM1: G = Abf @ Wbf^T   (M=8192, N=5120, K=2048; xh region K=1024)
    gemm1<<<640, 512, 0, stream>>>(Abf, Wbf, G);

    // fused softmax/hat + rh (wave per row)
    row_pass<<<B_ROWS / 4, 256, 0, stream>>>(G, bias_c, bias_hat, bias_r, hidden, rhbf);

    // GEMM2 + final epilogue -> out
    gemm2_final<<<dim3(8, 128), 256, 0, stream>>>(rhbf, Whhbf, G, bias_z, bias_h,
                                                  hidden, out);
}